// Round 7
// baseline (149.903 us; speedup 1.0000x reference)
//
#include <hip/hip_runtime.h>

#define BB 2
#define HH 16
#define SS 2048
#define DMODEL 1024

typedef unsigned short ushort_t;
typedef short bf16x8 __attribute__((ext_vector_type(8)));   // 8 bf16 = 4 VGPR
typedef float f32x4 __attribute__((ext_vector_type(4)));

__device__ __forceinline__ unsigned short f2bf(float f) {
  union { float f; unsigned int u; } x; x.f = f;
  unsigned int u = x.u;
  return (unsigned short)((u + 0x7fffu + ((u >> 16) & 1u)) >> 16);  // RNE
}
__device__ __forceinline__ unsigned int pack2(float a, float b) {
  return (unsigned int)f2bf(a) | ((unsigned int)f2bf(b) << 16);
}
// 2 f32 -> packed 2x bf16 in one instruction (gfx950; no builtin, T12 recipe)
__device__ __forceinline__ unsigned int cvtpk(float lo, float hi) {
  unsigned int r;
  asm("v_cvt_pk_bf16_f32 %0, %1, %2" : "=v"(r) : "v"(lo), "v"(hi));
  return r;
}
// async global->LDS, 16B per lane; LDS dest is wave-uniform base + lane*16
__device__ __forceinline__ void gload16(const ushort_t* g, ushort_t* l) {
  __builtin_amdgcn_global_load_lds(
      (const __attribute__((address_space(1))) void*)g,
      (__attribute__((address_space(3))) void*)l, 16, 0, 0);
}

// ---------------------------------------------------------------------------
// fp32 [B,S,H*64] -> bf16 Qh (pre-scaled by log2(e)/8), Kh [B,H,S,64];
// V -> Vt [B,H,64,S] with per-64-tile k-permutation matching attn's in-lane
// P layout (swapped-QK): Vt[d][64t + pi(m)] = V[64t + m][d],
// pi(c*16+g*4+r) = (c>>1)*32 + g*8 + (c&1)*4 + r.
// ---------------------------------------------------------------------------
__global__ void __launch_bounds__(256)
conv_qkv(const float* __restrict__ q, const float* __restrict__ k,
         const float* __restrict__ v, ushort_t* __restrict__ Qh,
         ushort_t* __restrict__ Kh, ushort_t* __restrict__ Vt) {
  const float c_sc = 0.18033688011112042f;  // log2(e)/sqrt(64): folded into Q
  __shared__ float vlds[64][65];  // +1 pad: conflict-free column reads
  int bh = blockIdx.y;
  int b = bh >> 4, h = bh & 15;
  int s0 = blockIdx.x * 64;
  int t = threadIdx.x;
#pragma unroll
  for (int j = 0; j < 4; ++j) {
    int idx = t + j * 256;
    int r = idx >> 4, c4 = idx & 15;  // 64 s-rows x 16 float4 of the 64-wide head slice
    size_t in_off = ((size_t)(b * SS + s0 + r)) * DMODEL + h * 64 + c4 * 4;
    float4 qa = *(const float4*)(q + in_off);
    float4 ka = *(const float4*)(k + in_off);
    float4 va = *(const float4*)(v + in_off);
    size_t out_off = ((size_t)bh * SS + s0 + r) * 64 + c4 * 4;
    *(uint2*)(Qh + out_off) = make_uint2(pack2(qa.x * c_sc, qa.y * c_sc),
                                         pack2(qa.z * c_sc, qa.w * c_sc));
    *(uint2*)(Kh + out_off) = make_uint2(pack2(ka.x, ka.y), pack2(ka.z, ka.w));
    vlds[r][c4 * 4 + 0] = va.x;
    vlds[r][c4 * 4 + 1] = va.y;
    vlds[r][c4 * 4 + 2] = va.z;
    vlds[r][c4 * 4 + 3] = va.w;
  }
  __syncthreads();
#pragma unroll
  for (int j = 0; j < 4; ++j) {
    int idx = t + j * 256;
    int d = idx >> 4, u = idx & 15;  // 64 d-rows x 16 chunks of 4 permuted-k
    // chunk u covers positions u*4..u*4+3  <-  orig rows m0..m0+3,
    // m0 = c*16 + g*4 with c = (u>>3)*2 + (u&1), g = (u>>1)&3.
    int c = ((u >> 3) << 1) | (u & 1);
    int g = (u >> 1) & 3;
    int m0 = c * 16 + g * 4;
    size_t voff = ((size_t)bh * 64 + d) * SS + s0 + u * 4;
    *(uint2*)(Vt + voff) =
        make_uint2(pack2(vlds[m0 + 0][d], vlds[m0 + 1][d]),
                   pack2(vlds[m0 + 2][d], vlds[m0 + 3][d]));
  }
}

// fp32 [1024,1024] -> bf16 same layout (rows of W == B^T-GEMM operand rows)
__global__ void __launch_bounds__(256)
conv_w(const float* __restrict__ w, ushort_t* __restrict__ wb) {
  int i = blockIdx.x * 256 + threadIdx.x;  // one thread per 8 elements
  float4 a = *(const float4*)(w + (size_t)i * 8);
  float4 b = *(const float4*)(w + (size_t)i * 8 + 4);
  uint4 o;
  o.x = pack2(a.x, a.y);
  o.y = pack2(a.z, a.w);
  o.z = pack2(b.x, b.y);
  o.w = pack2(b.z, b.w);
  *(uint4*)(wb + (size_t)i * 8) = o;
}

// ---------------------------------------------------------------------------
// Flash attention fwd, no-max online softmax. R6: in-block KV-split.
// 512 threads = 8 waves; q-tile 256 (64 rows/wave); waves 0-3 process kv
// tiles 0-15, waves 4-7 tiles 16-31 (each half has its own dbuf'd K/V LDS).
// Keeps R5's halved per-row LDS-fragment tax AND restores 2 waves/SIMD
// (R5 lesson: rows/wave x waves/SIMD is fixed on the Q axis — split KV).
// No-max softmax => partials add directly: o=o0+o1, l=l0+l1 via one LDS
// combine at the end. l via MFMA-with-ones (C-layout matches o).
// ---------------------------------------------------------------------------
__global__ void __launch_bounds__(512, 2)
attn_fwd(const ushort_t* __restrict__ Qh, const ushort_t* __restrict__ Kh,
         const ushort_t* __restrict__ Vt, ushort_t* __restrict__ ctx) {
  __shared__ ushort_t K_lds[2][2][64][64];  // [half][dbuf], 16 KB per half
  __shared__ ushort_t V_lds[2][2][64][64];
  __shared__ float cmb[4][64][21];          // combine buf, 21 pad (gcd(21,32)=1)
  int bh = blockIdx.y;
  int q0 = blockIdx.x * 256;
  int tid = threadIdx.x;
  int wid = tid >> 6;
  int half = wid >> 2;   // kv half: 0 -> tiles 0-15, 1 -> tiles 16-31
  int wq = wid & 3;      // q-row group within the half
  int lane = tid & 63;
  int g = lane >> 4, lr = lane & 15;
  int rsub = lane >> 3, ch = (lane & 7) ^ rsub;  // stage: row-in-8 / swizzled chunk

  const ushort_t* Qp = Qh + (size_t)bh * SS * 64;
  const ushort_t* Kp = Kh + (size_t)bh * SS * 64;
  const ushort_t* Vp = Vt + (size_t)bh * 64 * SS;

  ushort_t (*Kl)[64][64] = K_lds[half];  // this half's dbuf pair
  ushort_t (*Vl)[64][64] = V_lds[half];
  const int kvbase = half * (SS / 2);

  // Q fragments held in registers (64 rows/wave); B-operand of mfma(K,Q).
  bf16x8 qf[4][2];
#pragma unroll
  for (int qb = 0; qb < 4; ++qb) {
    int row = q0 + wq * 64 + qb * 16 + lr;
#pragma unroll
    for (int kk = 0; kk < 2; ++kk)
      qf[qb][kk] = *(const bf16x8*)(Qp + (size_t)row * 64 + kk * 32 + g * 8);
  }

  const f32x4 vzero = {0.f, 0.f, 0.f, 0.f};
  const short ob = (short)0x3F80;  // bf16 1.0
  const bf16x8 ones = {ob, ob, ob, ob, ob, ob, ob, ob};
  f32x4 o[4][4];
  f32x4 ol[4];  // l via mfma(P, ones): row=g*4+r=q, all cols equal
#pragma unroll
  for (int qb = 0; qb < 4; ++qb) {
    ol[qb] = vzero;
#pragma unroll
    for (int d = 0; d < 4; ++d) o[qb][d] = vzero;
  }

  // Stage one 64-kv tile for this half (4 waves x 4 gload16).
  // Pre-swizzled source: LDS[row][c] = G[row][c ^ (row&7)].
  auto stage = [&](int buf, int kv) {
#pragma unroll
    for (int j = 0; j < 2; ++j) {
      int i = j * 4 + wq;
      gload16(Kp + (size_t)(kv + i * 8 + rsub) * 64 + ch * 8, &Kl[buf][i * 8][0]);
      gload16(Vp + (size_t)(i * 8 + rsub) * SS + kv + ch * 8, &Vl[buf][i * 8][0]);
    }
  };

  const int NTH = SS / 128;  // 16 tiles per half
  auto tile = [&](int cur, int tl) {  // cur LITERAL at each call site
    if (tl + 1 < NTH) stage(cur ^ 1, kvbase + (tl + 1) * 64);

    // K/V fragments (swizzled read): logical [c*16+lr][kk*32+g*8..+8)
    bf16x8 kf[4][2], vf[4][2];
#pragma unroll
    for (int c = 0; c < 4; ++c)
#pragma unroll
      for (int kk = 0; kk < 2; ++kk) {
        kf[c][kk] = *(const bf16x8*)&Kl[cur][c * 16 + lr]
                                       [((kk * 4 + g) ^ (lr & 7)) * 8];
        vf[c][kk] = *(const bf16x8*)&Vl[cur][c * 16 + lr]
                                       [((kk * 4 + g) ^ (lr & 7)) * 8];
      }

#pragma unroll
    for (int qb = 0; qb < 4; ++qb) {
      // S^T = K·Q^T: lane holds s[c][r] = S[k=c*16+g*4+r][q=qb*16+lr]
      f32x4 s[4];
      __builtin_amdgcn_s_setprio(1);
#pragma unroll
      for (int c = 0; c < 4; ++c) {
        s[c] = __builtin_amdgcn_mfma_f32_16x16x32_bf16(kf[c][0], qf[qb][0], vzero, 0, 0, 0);
        s[c] = __builtin_amdgcn_mfma_f32_16x16x32_bf16(kf[c][1], qf[qb][1], s[c], 0, 0, 0);
      }
      __builtin_amdgcn_s_setprio(0);
      // exp (Q pre-scaled) + pack to PV A-fragments.
      float p[4][4];
#pragma unroll
      for (int c = 0; c < 4; ++c)
#pragma unroll
        for (int r = 0; r < 4; ++r) p[c][r] = __builtin_amdgcn_exp2f(s[c][r]);
      // pf[kk] elem j: (c,r) = (kk*2+(j>>2), j&3)  [pi-permutation, V matches]
      bf16x8 pf[2];
#pragma unroll
      for (int kk = 0; kk < 2; ++kk) {
        uint4 w;
        w.x = cvtpk(p[kk * 2][0], p[kk * 2][1]);
        w.y = cvtpk(p[kk * 2][2], p[kk * 2][3]);
        w.z = cvtpk(p[kk * 2 + 1][0], p[kk * 2 + 1][1]);
        w.w = cvtpk(p[kk * 2 + 1][2], p[kk * 2 + 1][3]);
        pf[kk] = *(bf16x8*)&w;
      }
      // PV + l: o += P·V_perm ; ol += P·1  (same C-layout as o)
      __builtin_amdgcn_s_setprio(1);
      ol[qb] = __builtin_amdgcn_mfma_f32_16x16x32_bf16(pf[0], ones, ol[qb], 0, 0, 0);
      ol[qb] = __builtin_amdgcn_mfma_f32_16x16x32_bf16(pf[1], ones, ol[qb], 0, 0, 0);
#pragma unroll
      for (int d = 0; d < 4; ++d) {
        o[qb][d] = __builtin_amdgcn_mfma_f32_16x16x32_bf16(pf[0], vf[d][0], o[qb][d], 0, 0, 0);
        o[qb][d] = __builtin_amdgcn_mfma_f32_16x16x32_bf16(pf[1], vf[d][1], o[qb][d], 0, 0, 0);
      }
      __builtin_amdgcn_s_setprio(0);
    }
    // both halves: staged buf drained at the barrier (vmcnt 0 before s_barrier)
    __syncthreads();
  };

  stage(0, kvbase);
  __syncthreads();  // buf0 ready for both halves
#pragma unroll 1
  for (int tl = 0; tl < NTH; tl += 2) {
    tile(0, tl);      // literal buffer indices: ds addrs = base + imm offset
    tile(1, tl + 1);
  }

  // Combine halves (partials directly addable: no-max softmax) + epilogue.
  int b = bh >> 4, h = bh & 15;
#pragma unroll 1
  for (int qb = 0; qb < 4; ++qb) {
    if (half) {
#pragma unroll
      for (int d = 0; d < 4; ++d)
#pragma unroll
        for (int r = 0; r < 4; ++r) cmb[wq][lane][d * 4 + r] = o[qb][d][r];
#pragma unroll
      for (int r = 0; r < 4; ++r) cmb[wq][lane][16 + r] = ol[qb][r];
    }
    __syncthreads();
    if (!half) {
      float linv[4];
#pragma unroll
      for (int r = 0; r < 4; ++r)
        linv[r] = __builtin_amdgcn_rcpf(ol[qb][r] + cmb[wq][lane][16 + r]);
#pragma unroll
      for (int d = 0; d < 4; ++d)
#pragma unroll
        for (int r = 0; r < 4; ++r) {
          float val = (o[qb][d][r] + cmb[wq][lane][d * 4 + r]) * linv[r];
          size_t row = (size_t)b * SS + q0 + wq * 64 + qb * 16 + g * 4 + r;
          ctx[row * DMODEL + h * 64 + d * 16 + lr] = f2bf(val);
        }
    }
    __syncthreads();
  }
}

// ---------------------------------------------------------------------------
// out[4096,1024] fp32 = ctx_bf16[4096,1024] @ Wb^T   (B^T-layout GEMM)
// 128x128 tile, BK=64, 4 waves of 64x64, global_load_lds staging (2-phase
// dbuf, pre-swizzled source, swizzled b128 reads).
// ---------------------------------------------------------------------------
__global__ void __launch_bounds__(256)
proj_gemm(const ushort_t* __restrict__ A, const ushort_t* __restrict__ Bw,
          float* __restrict__ out) {
  __shared__ ushort_t At[2][128][64];
  __shared__ ushort_t Bt[2][128][64];
  int m0 = blockIdx.x * 128, n0 = blockIdx.y * 128;
  int t = threadIdx.x;
  int wid = t >> 6, lane = t & 63;
  int wr = wid >> 1, wc = wid & 1;
  int g = lane >> 4, lr = lane & 15;
  int rsub = lane >> 3, ch = (lane & 7) ^ rsub;
  const f32x4 vzero = {0.f, 0.f, 0.f, 0.f};
  f32x4 acc[4][4];
#pragma unroll
  for (int m = 0; m < 4; ++m)
#pragma unroll
    for (int n = 0; n < 4; ++n) acc[m][n] = vzero;

  auto stage = [&](int buf, int k0) {
#pragma unroll
    for (int j = 0; j < 4; ++j) {
      int i = j * 4 + wid;  // 16 row-groups of 8 rows
      gload16(A + (size_t)(m0 + i * 8 + rsub) * DMODEL + k0 + ch * 8, &At[buf][i * 8][0]);
      gload16(Bw + (size_t)(n0 + i * 8 + rsub) * DMODEL + k0 + ch * 8, &Bt[buf][i * 8][0]);
    }
  };

  const int NTK = DMODEL / 64;  // 16
  auto step = [&](int cur, int kt) {
    if (kt + 1 < NTK) stage(cur ^ 1, (kt + 1) * 64);
#pragma unroll
    for (int kk = 0; kk < 2; ++kk) {
      bf16x8 af[4], bf[4];
#pragma unroll
      for (int m = 0; m < 4; ++m)
        af[m] = *(const bf16x8*)&At[cur][wr * 64 + m * 16 + lr]
                                      [((kk * 4 + g) ^ (lr & 7)) * 8];
#pragma unroll
      for (int n = 0; n < 4; ++n)
        bf[n] = *(const bf16x8*)&Bt[cur][wc * 64 + n * 16 + lr]
                                      [((kk * 4 + g) ^ (lr & 7)) * 8];
#pragma unroll
      for (int m = 0; m < 4; ++m)
#pragma unroll
        for (int n = 0; n < 4; ++n)
          acc[m][n] = __builtin_amdgcn_mfma_f32_16x16x32_bf16(af[m], bf[n], acc[m][n], 0, 0, 0);
    }
    __syncthreads();
  };

  stage(0, 0);
  __syncthreads();
#pragma unroll 1
  for (int kt = 0; kt < NTK; kt += 2) {
    step(0, kt);
    step(1, kt + 1);
  }
#pragma unroll
  for (int m = 0; m < 4; ++m)
#pragma unroll
    for (int n = 0; n < 4; ++n)
#pragma unroll
      for (int r = 0; r < 4; ++r)
        out[(size_t)(m0 + wr * 64 + m * 16 + g * 4 + r) * DMODEL +
            n0 + wc * 64 + n * 16 + lr] = acc[m][n][r];
}

extern "C" void kernel_launch(void* const* d_in, const int* in_sizes, int n_in,
                              void* d_out, int out_size, void* d_ws, size_t ws_size,
                              hipStream_t stream) {
  const float* q = (const float*)d_in[0];
  const float* k = (const float*)d_in[1];
  const float* v = (const float*)d_in[2];
  const float* w = (const float*)d_in[3];
  float* out = (float*)d_out;

  size_t nqk = (size_t)BB * HH * SS * 64;  // 4,194,304 elems per tensor
  ushort_t* Qh = (ushort_t*)d_ws;
  ushort_t* Kh = Qh + nqk;
  ushort_t* Vt = Kh + nqk;
  ushort_t* ctx = Vt + nqk;
  ushort_t* Wb = ctx + (size_t)BB * SS * DMODEL;
  size_t need = (4 * nqk + (size_t)DMODEL * DMODEL) * sizeof(ushort_t);  // ~34 MB
  if (ws_size < need) return;

  conv_qkv<<<dim3(SS / 64, BB * HH), 256, 0, stream>>>(q, k, v, Qh, Kh, Vt);
  conv_w<<<(DMODEL * DMODEL / 8) / 256, 256, 0, stream>>>(w, Wb);
  attn_fwd<<<dim3(SS / 256, BB * HH), 512, 0, stream>>>(Qh, Kh, Vt, ctx);
  proj_gemm<<<dim3((BB * SS) / 128, DMODEL / 128), 256, 0, stream>>>(ctx, Wb, out);
}

// Round 8
// 149.573 us; speedup vs baseline: 1.0022x; 1.0022x over previous
//
#include <hip/hip_runtime.h>

#define BB 2
#define HH 16
#define SS 2048
#define DMODEL 1024

typedef unsigned short ushort_t;
typedef short bf16x8 __attribute__((ext_vector_type(8)));   // 8 bf16 = 4 VGPR
typedef float f32x4 __attribute__((ext_vector_type(4)));

__device__ __forceinline__ unsigned short f2bf(float f) {
  union { float f; unsigned int u; } x; x.f = f;
  unsigned int u = x.u;
  return (unsigned short)((u + 0x7fffu + ((u >> 16) & 1u)) >> 16);  // RNE
}
__device__ __forceinline__ unsigned int pack2(float a, float b) {
  return (unsigned int)f2bf(a) | ((unsigned int)f2bf(b) << 16);
}
// 2 f32 -> packed 2x bf16 in one instruction (gfx950; no builtin, T12 recipe)
__device__ __forceinline__ unsigned int cvtpk(float lo, float hi) {
  unsigned int r;
  asm("v_cvt_pk_bf16_f32 %0, %1, %2" : "=v"(r) : "v"(lo), "v"(hi));
  return r;
}
// async global->LDS, 16B per lane; LDS dest is wave-uniform base + lane*16
__device__ __forceinline__ void gload16(const ushort_t* g, ushort_t* l) {
  __builtin_amdgcn_global_load_lds(
      (const __attribute__((address_space(1))) void*)g,
      (__attribute__((address_space(3))) void*)l, 16, 0, 0);
}

// ---------------------------------------------------------------------------
// fp32 [B,S,H*64] -> bf16 Qh (pre-scaled by log2(e)/8), Kh [B,H,S,64];
// V -> Vt [B,H,64,S] with per-64-tile k-permutation matching attn's in-lane
// P layout (swapped-QK): Vt[d][64t + pi(m)] = V[64t + m][d],
// pi(c*16+g*4+r) = (c>>1)*32 + g*8 + (c&1)*4 + r.
// ---------------------------------------------------------------------------
__global__ void __launch_bounds__(256)
conv_qkv(const float* __restrict__ q, const float* __restrict__ k,
         const float* __restrict__ v, ushort_t* __restrict__ Qh,
         ushort_t* __restrict__ Kh, ushort_t* __restrict__ Vt) {
  const float c_sc = 0.18033688011112042f;  // log2(e)/sqrt(64): folded into Q
  __shared__ float vlds[64][65];  // +1 pad: conflict-free column reads
  int bh = blockIdx.y;
  int b = bh >> 4, h = bh & 15;
  int s0 = blockIdx.x * 64;
  int t = threadIdx.x;
#pragma unroll
  for (int j = 0; j < 4; ++j) {
    int idx = t + j * 256;
    int r = idx >> 4, c4 = idx & 15;  // 64 s-rows x 16 float4 of the 64-wide head slice
    size_t in_off = ((size_t)(b * SS + s0 + r)) * DMODEL + h * 64 + c4 * 4;
    float4 qa = *(const float4*)(q + in_off);
    float4 ka = *(const float4*)(k + in_off);
    float4 va = *(const float4*)(v + in_off);
    size_t out_off = ((size_t)bh * SS + s0 + r) * 64 + c4 * 4;
    *(uint2*)(Qh + out_off) = make_uint2(pack2(qa.x * c_sc, qa.y * c_sc),
                                         pack2(qa.z * c_sc, qa.w * c_sc));
    *(uint2*)(Kh + out_off) = make_uint2(pack2(ka.x, ka.y), pack2(ka.z, ka.w));
    vlds[r][c4 * 4 + 0] = va.x;
    vlds[r][c4 * 4 + 1] = va.y;
    vlds[r][c4 * 4 + 2] = va.z;
    vlds[r][c4 * 4 + 3] = va.w;
  }
  __syncthreads();
#pragma unroll
  for (int j = 0; j < 4; ++j) {
    int idx = t + j * 256;
    int d = idx >> 4, u = idx & 15;  // 64 d-rows x 16 chunks of 4 permuted-k
    // chunk u covers positions u*4..u*4+3  <-  orig rows m0..m0+3,
    // m0 = c*16 + g*4 with c = (u>>3)*2 + (u&1), g = (u>>1)&3.
    int c = ((u >> 3) << 1) | (u & 1);
    int g = (u >> 1) & 3;
    int m0 = c * 16 + g * 4;
    size_t voff = ((size_t)bh * 64 + d) * SS + s0 + u * 4;
    *(uint2*)(Vt + voff) =
        make_uint2(pack2(vlds[m0 + 0][d], vlds[m0 + 1][d]),
                   pack2(vlds[m0 + 2][d], vlds[m0 + 3][d]));
  }
}

// fp32 [1024,1024] -> bf16 same layout (rows of W == B^T-GEMM operand rows)
__global__ void __launch_bounds__(256)
conv_w(const float* __restrict__ w, ushort_t* __restrict__ wb) {
  int i = blockIdx.x * 256 + threadIdx.x;  // one thread per 8 elements
  float4 a = *(const float4*)(w + (size_t)i * 8);
  float4 b = *(const float4*)(w + (size_t)i * 8 + 4);
  uint4 o;
  o.x = pack2(a.x, a.y);
  o.y = pack2(a.z, a.w);
  o.z = pack2(b.x, b.y);
  o.w = pack2(b.z, b.w);
  *(uint4*)(wb + (size_t)i * 8) = o;
}

// ---------------------------------------------------------------------------
// Flash attention fwd, no-max online softmax. In-block KV-split:
// 512 threads = 8 waves; q-tile 256 (64 rows/wave); waves 0-3 process kv
// tiles 0-15, waves 4-7 tiles 16-31 (each half has its own dbuf'd K/V LDS).
// R7 FIX: __launch_bounds__(512, 1) — R6's (512,2) capped VGPR at 128 and
// spilled the accumulators (WRITE_SIZE 8MB -> 565MB scratch, 2x slower).
// 1 block/CU (grid 256 = #CU), 8 waves/CU = 2/SIMD, VGPR cap 256, no spill.
// No-max softmax => partials add directly: o=o0+o1, l=l0+l1 via one LDS
// combine at the end. l via MFMA-with-ones (C-layout matches o).
// ---------------------------------------------------------------------------
__global__ void __launch_bounds__(512, 1)
attn_fwd(const ushort_t* __restrict__ Qh, const ushort_t* __restrict__ Kh,
         const ushort_t* __restrict__ Vt, ushort_t* __restrict__ ctx) {
  __shared__ ushort_t K_lds[2][2][64][64];  // [half][dbuf], 16 KB per half
  __shared__ ushort_t V_lds[2][2][64][64];
  __shared__ float cmb[4][64][21];          // combine buf, 21 pad (gcd(21,32)=1)
  int bh = blockIdx.y;
  int q0 = blockIdx.x * 256;
  int tid = threadIdx.x;
  int wid = tid >> 6;
  int half = wid >> 2;   // kv half: 0 -> tiles 0-15, 1 -> tiles 16-31
  int wq = wid & 3;      // q-row group within the half
  int lane = tid & 63;
  int g = lane >> 4, lr = lane & 15;
  int rsub = lane >> 3, ch = (lane & 7) ^ rsub;  // stage: row-in-8 / swizzled chunk

  const ushort_t* Qp = Qh + (size_t)bh * SS * 64;
  const ushort_t* Kp = Kh + (size_t)bh * SS * 64;
  const ushort_t* Vp = Vt + (size_t)bh * 64 * SS;

  ushort_t (*Kl)[64][64] = K_lds[half];  // this half's dbuf pair
  ushort_t (*Vl)[64][64] = V_lds[half];
  const int kvbase = half * (SS / 2);

  // Q fragments held in registers (64 rows/wave); B-operand of mfma(K,Q).
  bf16x8 qf[4][2];
#pragma unroll
  for (int qb = 0; qb < 4; ++qb) {
    int row = q0 + wq * 64 + qb * 16 + lr;
#pragma unroll
    for (int kk = 0; kk < 2; ++kk)
      qf[qb][kk] = *(const bf16x8*)(Qp + (size_t)row * 64 + kk * 32 + g * 8);
  }

  const f32x4 vzero = {0.f, 0.f, 0.f, 0.f};
  const short ob = (short)0x3F80;  // bf16 1.0
  const bf16x8 ones = {ob, ob, ob, ob, ob, ob, ob, ob};
  f32x4 o[4][4];
  f32x4 ol[4];  // l via mfma(P, ones): row=g*4+r=q, all cols equal
#pragma unroll
  for (int qb = 0; qb < 4; ++qb) {
    ol[qb] = vzero;
#pragma unroll
    for (int d = 0; d < 4; ++d) o[qb][d] = vzero;
  }

  // Stage one 64-kv tile for this half (4 waves x 4 gload16).
  // Pre-swizzled source: LDS[row][c] = G[row][c ^ (row&7)].
  auto stage = [&](int buf, int kv) {
#pragma unroll
    for (int j = 0; j < 2; ++j) {
      int i = j * 4 + wq;
      gload16(Kp + (size_t)(kv + i * 8 + rsub) * 64 + ch * 8, &Kl[buf][i * 8][0]);
      gload16(Vp + (size_t)(i * 8 + rsub) * SS + kv + ch * 8, &Vl[buf][i * 8][0]);
    }
  };

  const int NTH = SS / 128;  // 16 tiles per half
  auto tile = [&](int cur, int tl) {  // cur LITERAL at each call site
    if (tl + 1 < NTH) stage(cur ^ 1, kvbase + (tl + 1) * 64);

    // K/V fragments (swizzled read): logical [c*16+lr][kk*32+g*8..+8)
    bf16x8 kf[4][2], vf[4][2];
#pragma unroll
    for (int c = 0; c < 4; ++c)
#pragma unroll
      for (int kk = 0; kk < 2; ++kk) {
        kf[c][kk] = *(const bf16x8*)&Kl[cur][c * 16 + lr]
                                       [((kk * 4 + g) ^ (lr & 7)) * 8];
        vf[c][kk] = *(const bf16x8*)&Vl[cur][c * 16 + lr]
                                       [((kk * 4 + g) ^ (lr & 7)) * 8];
      }

#pragma unroll
    for (int qb = 0; qb < 4; ++qb) {
      // S^T = K·Q^T: lane holds s[c][r] = S[k=c*16+g*4+r][q=qb*16+lr]
      f32x4 s[4];
      __builtin_amdgcn_s_setprio(1);
#pragma unroll
      for (int c = 0; c < 4; ++c) {
        s[c] = __builtin_amdgcn_mfma_f32_16x16x32_bf16(kf[c][0], qf[qb][0], vzero, 0, 0, 0);
        s[c] = __builtin_amdgcn_mfma_f32_16x16x32_bf16(kf[c][1], qf[qb][1], s[c], 0, 0, 0);
      }
      __builtin_amdgcn_s_setprio(0);
      // exp (Q pre-scaled) + pack to PV A-fragments.
      float p[4][4];
#pragma unroll
      for (int c = 0; c < 4; ++c)
#pragma unroll
        for (int r = 0; r < 4; ++r) p[c][r] = __builtin_amdgcn_exp2f(s[c][r]);
      // pf[kk] elem j: (c,r) = (kk*2+(j>>2), j&3)  [pi-permutation, V matches]
      bf16x8 pf[2];
#pragma unroll
      for (int kk = 0; kk < 2; ++kk) {
        uint4 w;
        w.x = cvtpk(p[kk * 2][0], p[kk * 2][1]);
        w.y = cvtpk(p[kk * 2][2], p[kk * 2][3]);
        w.z = cvtpk(p[kk * 2 + 1][0], p[kk * 2 + 1][1]);
        w.w = cvtpk(p[kk * 2 + 1][2], p[kk * 2 + 1][3]);
        pf[kk] = *(bf16x8*)&w;
      }
      // PV + l: o += P·V_perm ; ol += P·1  (same C-layout as o)
      __builtin_amdgcn_s_setprio(1);
      ol[qb] = __builtin_amdgcn_mfma_f32_16x16x32_bf16(pf[0], ones, ol[qb], 0, 0, 0);
      ol[qb] = __builtin_amdgcn_mfma_f32_16x16x32_bf16(pf[1], ones, ol[qb], 0, 0, 0);
#pragma unroll
      for (int d = 0; d < 4; ++d) {
        o[qb][d] = __builtin_amdgcn_mfma_f32_16x16x32_bf16(pf[0], vf[d][0], o[qb][d], 0, 0, 0);
        o[qb][d] = __builtin_amdgcn_mfma_f32_16x16x32_bf16(pf[1], vf[d][1], o[qb][d], 0, 0, 0);
      }
      __builtin_amdgcn_s_setprio(0);
    }
    // both halves: staged buf drained at the barrier (vmcnt 0 before s_barrier)
    __syncthreads();
  };

  stage(0, kvbase);
  __syncthreads();  // buf0 ready for both halves
#pragma unroll 1
  for (int tl = 0; tl < NTH; tl += 2) {
    tile(0, tl);      // literal buffer indices: ds addrs = base + imm offset
    tile(1, tl + 1);
  }

  // Combine halves (partials directly addable: no-max softmax) + epilogue.
  int b = bh >> 4, h = bh & 15;
#pragma unroll 1
  for (int qb = 0; qb < 4; ++qb) {
    if (half) {
#pragma unroll
      for (int d = 0; d < 4; ++d)
#pragma unroll
        for (int r = 0; r < 4; ++r) cmb[wq][lane][d * 4 + r] = o[qb][d][r];
#pragma unroll
      for (int r = 0; r < 4; ++r) cmb[wq][lane][16 + r] = ol[qb][r];
    }
    __syncthreads();
    if (!half) {
      float linv[4];
#pragma unroll
      for (int r = 0; r < 4; ++r)
        linv[r] = __builtin_amdgcn_rcpf(ol[qb][r] + cmb[wq][lane][16 + r]);
#pragma unroll
      for (int d = 0; d < 4; ++d)
#pragma unroll
        for (int r = 0; r < 4; ++r) {
          float val = (o[qb][d][r] + cmb[wq][lane][d * 4 + r]) * linv[r];
          size_t row = (size_t)b * SS + q0 + wq * 64 + qb * 16 + g * 4 + r;
          ctx[row * DMODEL + h * 64 + d * 16 + lr] = f2bf(val);
        }
    }
    __syncthreads();
  }
}

// ---------------------------------------------------------------------------
// out[4096,1024] fp32 = ctx_bf16[4096,1024] @ Wb^T   (B^T-layout GEMM)
// 128x128 tile, BK=64, 4 waves of 64x64, global_load_lds staging (2-phase
// dbuf, pre-swizzled source, swizzled b128 reads).
// ---------------------------------------------------------------------------
__global__ void __launch_bounds__(256)
proj_gemm(const ushort_t* __restrict__ A, const ushort_t* __restrict__ Bw,
          float* __restrict__ out) {
  __shared__ ushort_t At[2][128][64];
  __shared__ ushort_t Bt[2][128][64];
  int m0 = blockIdx.x * 128, n0 = blockIdx.y * 128;
  int t = threadIdx.x;
  int wid = t >> 6, lane = t & 63;
  int wr = wid >> 1, wc = wid & 1;
  int g = lane >> 4, lr = lane & 15;
  int rsub = lane >> 3, ch = (lane & 7) ^ rsub;
  const f32x4 vzero = {0.f, 0.f, 0.f, 0.f};
  f32x4 acc[4][4];
#pragma unroll
  for (int m = 0; m < 4; ++m)
#pragma unroll
    for (int n = 0; n < 4; ++n) acc[m][n] = vzero;

  auto stage = [&](int buf, int k0) {
#pragma unroll
    for (int j = 0; j < 4; ++j) {
      int i = j * 4 + wid;  // 16 row-groups of 8 rows
      gload16(A + (size_t)(m0 + i * 8 + rsub) * DMODEL + k0 + ch * 8, &At[buf][i * 8][0]);
      gload16(Bw + (size_t)(n0 + i * 8 + rsub) * DMODEL + k0 + ch * 8, &Bt[buf][i * 8][0]);
    }
  };

  const int NTK = DMODEL / 64;  // 16
  auto step = [&](int cur, int kt) {
    if (kt + 1 < NTK) stage(cur ^ 1, (kt + 1) * 64);
#pragma unroll
    for (int kk = 0; kk < 2; ++kk) {
      bf16x8 af[4], bf[4];
#pragma unroll
      for (int m = 0; m < 4; ++m)
        af[m] = *(const bf16x8*)&At[cur][wr * 64 + m * 16 + lr]
                                      [((kk * 4 + g) ^ (lr & 7)) * 8];
#pragma unroll
      for (int n = 0; n < 4; ++n)
        bf[n] = *(const bf16x8*)&Bt[cur][wc * 64 + n * 16 + lr]
                                      [((kk * 4 + g) ^ (lr & 7)) * 8];
#pragma unroll
      for (int m = 0; m < 4; ++m)
#pragma unroll
        for (int n = 0; n < 4; ++n)
          acc[m][n] = __builtin_amdgcn_mfma_f32_16x16x32_bf16(af[m], bf[n], acc[m][n], 0, 0, 0);
    }
    __syncthreads();
  };

  stage(0, 0);
  __syncthreads();
#pragma unroll 1
  for (int kt = 0; kt < NTK; kt += 2) {
    step(0, kt);
    step(1, kt + 1);
  }
#pragma unroll
  for (int m = 0; m < 4; ++m)
#pragma unroll
    for (int n = 0; n < 4; ++n)
#pragma unroll
      for (int r = 0; r < 4; ++r)
        out[(size_t)(m0 + wr * 64 + m * 16 + g * 4 + r) * DMODEL +
            n0 + wc * 64 + n * 16 + lr] = acc[m][n][r];
}

extern "C" void kernel_launch(void* const* d_in, const int* in_sizes, int n_in,
                              void* d_out, int out_size, void* d_ws, size_t ws_size,
                              hipStream_t stream) {
  const float* q = (const float*)d_in[0];
  const float* k = (const float*)d_in[1];
  const float* v = (const float*)d_in[2];
  const float* w = (const float*)d_in[3];
  float* out = (float*)d_out;

  size_t nqk = (size_t)BB * HH * SS * 64;  // 4,194,304 elems per tensor
  ushort_t* Qh = (ushort_t*)d_ws;
  ushort_t* Kh = Qh + nqk;
  ushort_t* Vt = Kh + nqk;
  ushort_t* ctx = Vt + nqk;
  ushort_t* Wb = ctx + (size_t)BB * SS * DMODEL;
  size_t need = (4 * nqk + (size_t)DMODEL * DMODEL) * sizeof(ushort_t);  // ~34 MB
  if (ws_size < need) return;

  conv_qkv<<<dim3(SS / 64, BB * HH), 256, 0, stream>>>(q, k, v, Qh, Kh, Vt);
  conv_w<<<(DMODEL * DMODEL / 8) / 256, 256, 0, stream>>>(w, Wb);
  attn_fwd<<<dim3(SS / 256, BB * HH), 512, 0, stream>>>(Qh, Kh, Vt, ctx);
  proj_gemm<<<dim3((BB * SS) / 128, DMODEL / 128), 256, 0, stream>>>(ctx, Wb, out);
}

// Round 9
// 76.909 us; speedup vs baseline: 1.9491x; 1.9448x over previous
//
#include <hip/hip_runtime.h>

#define BB 2
#define HH 16
#define SS 2048
#define DMODEL 1024

typedef unsigned short ushort_t;
typedef short bf16x8 __attribute__((ext_vector_type(8)));   // 8 bf16 = 4 VGPR
typedef float f32x4 __attribute__((ext_vector_type(4)));

__device__ __forceinline__ unsigned short f2bf(float f) {
  union { float f; unsigned int u; } x; x.f = f;
  unsigned int u = x.u;
  return (unsigned short)((u + 0x7fffu + ((u >> 16) & 1u)) >> 16);  // RNE
}
__device__ __forceinline__ unsigned int pack2(float a, float b) {
  return (unsigned int)f2bf(a) | ((unsigned int)f2bf(b) << 16);
}
// 2 f32 -> packed 2x bf16 in one instruction (gfx950; no builtin, T12 recipe)
__device__ __forceinline__ unsigned int cvtpk(float lo, float hi) {
  unsigned int r;
  asm("v_cvt_pk_bf16_f32 %0, %1, %2" : "=v"(r) : "v"(lo), "v"(hi));
  return r;
}
// async global->LDS, 16B per lane; LDS dest is wave-uniform base + lane*16
__device__ __forceinline__ void gload16(const ushort_t* g, ushort_t* l) {
  __builtin_amdgcn_global_load_lds(
      (const __attribute__((address_space(1))) void*)g,
      (__attribute__((address_space(3))) void*)l, 16, 0, 0);
}

// ---------------------------------------------------------------------------
// fp32 [B,S,H*64] -> bf16 Qh (pre-scaled by log2(e)/8), Kh [B,H,S,64];
// V -> Vt [B,H,64,S] with per-64-tile k-permutation matching attn's in-lane
// P layout (swapped-QK): Vt[d][64t + pi(m)] = V[64t + m][d],
// pi(c*16+g*4+r) = (c>>1)*32 + g*8 + (c&1)*4 + r.
// ---------------------------------------------------------------------------
__global__ void __launch_bounds__(256)
conv_qkv(const float* __restrict__ q, const float* __restrict__ k,
         const float* __restrict__ v, ushort_t* __restrict__ Qh,
         ushort_t* __restrict__ Kh, ushort_t* __restrict__ Vt) {
  const float c_sc = 0.18033688011112042f;  // log2(e)/sqrt(64): folded into Q
  __shared__ float vlds[64][65];  // +1 pad: conflict-free column reads
  int bh = blockIdx.y;
  int b = bh >> 4, h = bh & 15;
  int s0 = blockIdx.x * 64;
  int t = threadIdx.x;
#pragma unroll
  for (int j = 0; j < 4; ++j) {
    int idx = t + j * 256;
    int r = idx >> 4, c4 = idx & 15;  // 64 s-rows x 16 float4 of the 64-wide head slice
    size_t in_off = ((size_t)(b * SS + s0 + r)) * DMODEL + h * 64 + c4 * 4;
    float4 qa = *(const float4*)(q + in_off);
    float4 ka = *(const float4*)(k + in_off);
    float4 va = *(const float4*)(v + in_off);
    size_t out_off = ((size_t)bh * SS + s0 + r) * 64 + c4 * 4;
    *(uint2*)(Qh + out_off) = make_uint2(pack2(qa.x * c_sc, qa.y * c_sc),
                                         pack2(qa.z * c_sc, qa.w * c_sc));
    *(uint2*)(Kh + out_off) = make_uint2(pack2(ka.x, ka.y), pack2(ka.z, ka.w));
    vlds[r][c4 * 4 + 0] = va.x;
    vlds[r][c4 * 4 + 1] = va.y;
    vlds[r][c4 * 4 + 2] = va.z;
    vlds[r][c4 * 4 + 3] = va.w;
  }
  __syncthreads();
#pragma unroll
  for (int j = 0; j < 4; ++j) {
    int idx = t + j * 256;
    int d = idx >> 4, u = idx & 15;  // 64 d-rows x 16 chunks of 4 permuted-k
    // chunk u covers positions u*4..u*4+3  <-  orig rows m0..m0+3,
    // m0 = c*16 + g*4 with c = (u>>3)*2 + (u&1), g = (u>>1)&3.
    int c = ((u >> 3) << 1) | (u & 1);
    int g = (u >> 1) & 3;
    int m0 = c * 16 + g * 4;
    size_t voff = ((size_t)bh * 64 + d) * SS + s0 + u * 4;
    *(uint2*)(Vt + voff) =
        make_uint2(pack2(vlds[m0 + 0][d], vlds[m0 + 1][d]),
                   pack2(vlds[m0 + 2][d], vlds[m0 + 3][d]));
  }
}

// fp32 [1024,1024] -> bf16 same layout (rows of W == B^T-GEMM operand rows)
__global__ void __launch_bounds__(256)
conv_w(const float* __restrict__ w, ushort_t* __restrict__ wb) {
  int i = blockIdx.x * 256 + threadIdx.x;  // one thread per 8 elements
  float4 a = *(const float4*)(w + (size_t)i * 8);
  float4 b = *(const float4*)(w + (size_t)i * 8 + 4);
  uint4 o;
  o.x = pack2(a.x, a.y);
  o.y = pack2(a.z, a.w);
  o.z = pack2(b.x, b.y);
  o.w = pack2(b.z, b.w);
  *(uint4*)(wb + (size_t)i * 8) = o;
}

// ---------------------------------------------------------------------------
// Flash attention fwd, no-max online softmax. In-block KV-split:
// 512 threads = 8 waves; q-tile 256 (64 rows/wave); waves 0-3 process kv
// tiles 0-15, waves 4-7 tiles 16-31 (each half has its own dbuf'd K/V LDS).
// R8 FIX (rule #20): R6's epilogue used `#pragma unroll 1` with runtime qb
// indexing o[qb]/ol[qb] -> the MFMA ACCUMULATORS were allocated to scratch
// (VGPR 156->116, WRITE_SIZE 8MB->565MB, every tile's accumulation through
// local memory). R7's launch-bounds change was a wrong diagnosis (counters
// identical). Full unroll => static indices => accumulators back in VGPRs.
// No-max softmax => partials add directly: o=o0+o1, l=l0+l1 via one LDS
// combine at the end. l via MFMA-with-ones (C-layout matches o).
// ---------------------------------------------------------------------------
__global__ void __launch_bounds__(512, 1)
attn_fwd(const ushort_t* __restrict__ Qh, const ushort_t* __restrict__ Kh,
         const ushort_t* __restrict__ Vt, ushort_t* __restrict__ ctx) {
  __shared__ ushort_t K_lds[2][2][64][64];  // [half][dbuf], 16 KB per half
  __shared__ ushort_t V_lds[2][2][64][64];
  __shared__ float cmb[4][64][21];          // combine buf, 21 pad (gcd(21,32)=1)
  int bh = blockIdx.y;
  int q0 = blockIdx.x * 256;
  int tid = threadIdx.x;
  int wid = tid >> 6;
  int half = wid >> 2;   // kv half: 0 -> tiles 0-15, 1 -> tiles 16-31
  int wq = wid & 3;      // q-row group within the half
  int lane = tid & 63;
  int g = lane >> 4, lr = lane & 15;
  int rsub = lane >> 3, ch = (lane & 7) ^ rsub;  // stage: row-in-8 / swizzled chunk

  const ushort_t* Qp = Qh + (size_t)bh * SS * 64;
  const ushort_t* Kp = Kh + (size_t)bh * SS * 64;
  const ushort_t* Vp = Vt + (size_t)bh * 64 * SS;

  ushort_t (*Kl)[64][64] = K_lds[half];  // this half's dbuf pair
  ushort_t (*Vl)[64][64] = V_lds[half];
  const int kvbase = half * (SS / 2);

  // Q fragments held in registers (64 rows/wave); B-operand of mfma(K,Q).
  bf16x8 qf[4][2];
#pragma unroll
  for (int qb = 0; qb < 4; ++qb) {
    int row = q0 + wq * 64 + qb * 16 + lr;
#pragma unroll
    for (int kk = 0; kk < 2; ++kk)
      qf[qb][kk] = *(const bf16x8*)(Qp + (size_t)row * 64 + kk * 32 + g * 8);
  }

  const f32x4 vzero = {0.f, 0.f, 0.f, 0.f};
  const short ob = (short)0x3F80;  // bf16 1.0
  const bf16x8 ones = {ob, ob, ob, ob, ob, ob, ob, ob};
  f32x4 o[4][4];
  f32x4 ol[4];  // l via mfma(P, ones): row=g*4+r=q, all cols equal
#pragma unroll
  for (int qb = 0; qb < 4; ++qb) {
    ol[qb] = vzero;
#pragma unroll
    for (int d = 0; d < 4; ++d) o[qb][d] = vzero;
  }

  // Stage one 64-kv tile for this half (4 waves x 4 gload16).
  // Pre-swizzled source: LDS[row][c] = G[row][c ^ (row&7)].
  auto stage = [&](int buf, int kv) {
#pragma unroll
    for (int j = 0; j < 2; ++j) {
      int i = j * 4 + wq;
      gload16(Kp + (size_t)(kv + i * 8 + rsub) * 64 + ch * 8, &Kl[buf][i * 8][0]);
      gload16(Vp + (size_t)(i * 8 + rsub) * SS + kv + ch * 8, &Vl[buf][i * 8][0]);
    }
  };

  const int NTH = SS / 128;  // 16 tiles per half
  auto tile = [&](int cur, int tl) {  // cur LITERAL at each call site
    if (tl + 1 < NTH) stage(cur ^ 1, kvbase + (tl + 1) * 64);

    // K/V fragments (swizzled read): logical [c*16+lr][kk*32+g*8..+8)
    bf16x8 kf[4][2], vf[4][2];
#pragma unroll
    for (int c = 0; c < 4; ++c)
#pragma unroll
      for (int kk = 0; kk < 2; ++kk) {
        kf[c][kk] = *(const bf16x8*)&Kl[cur][c * 16 + lr]
                                       [((kk * 4 + g) ^ (lr & 7)) * 8];
        vf[c][kk] = *(const bf16x8*)&Vl[cur][c * 16 + lr]
                                       [((kk * 4 + g) ^ (lr & 7)) * 8];
      }

#pragma unroll
    for (int qb = 0; qb < 4; ++qb) {
      // S^T = K·Q^T: lane holds s[c][r] = S[k=c*16+g*4+r][q=qb*16+lr]
      f32x4 s[4];
      __builtin_amdgcn_s_setprio(1);
#pragma unroll
      for (int c = 0; c < 4; ++c) {
        s[c] = __builtin_amdgcn_mfma_f32_16x16x32_bf16(kf[c][0], qf[qb][0], vzero, 0, 0, 0);
        s[c] = __builtin_amdgcn_mfma_f32_16x16x32_bf16(kf[c][1], qf[qb][1], s[c], 0, 0, 0);
      }
      __builtin_amdgcn_s_setprio(0);
      // exp (Q pre-scaled) + pack to PV A-fragments.
      float p[4][4];
#pragma unroll
      for (int c = 0; c < 4; ++c)
#pragma unroll
        for (int r = 0; r < 4; ++r) p[c][r] = __builtin_amdgcn_exp2f(s[c][r]);
      // pf[kk] elem j: (c,r) = (kk*2+(j>>2), j&3)  [pi-permutation, V matches]
      bf16x8 pf[2];
#pragma unroll
      for (int kk = 0; kk < 2; ++kk) {
        uint4 w;
        w.x = cvtpk(p[kk * 2][0], p[kk * 2][1]);
        w.y = cvtpk(p[kk * 2][2], p[kk * 2][3]);
        w.z = cvtpk(p[kk * 2 + 1][0], p[kk * 2 + 1][1]);
        w.w = cvtpk(p[kk * 2 + 1][2], p[kk * 2 + 1][3]);
        pf[kk] = *(bf16x8*)&w;
      }
      // PV + l: o += P·V_perm ; ol += P·1  (same C-layout as o)
      __builtin_amdgcn_s_setprio(1);
      ol[qb] = __builtin_amdgcn_mfma_f32_16x16x32_bf16(pf[0], ones, ol[qb], 0, 0, 0);
      ol[qb] = __builtin_amdgcn_mfma_f32_16x16x32_bf16(pf[1], ones, ol[qb], 0, 0, 0);
#pragma unroll
      for (int d = 0; d < 4; ++d) {
        o[qb][d] = __builtin_amdgcn_mfma_f32_16x16x32_bf16(pf[0], vf[d][0], o[qb][d], 0, 0, 0);
        o[qb][d] = __builtin_amdgcn_mfma_f32_16x16x32_bf16(pf[1], vf[d][1], o[qb][d], 0, 0, 0);
      }
      __builtin_amdgcn_s_setprio(0);
    }
    // both halves: staged buf drained at the barrier (vmcnt 0 before s_barrier)
    __syncthreads();
  };

  stage(0, kvbase);
  __syncthreads();  // buf0 ready for both halves
#pragma unroll 1
  for (int tl = 0; tl < NTH; tl += 2) {
    tile(0, tl);      // literal buffer indices: ds addrs = base + imm offset
    tile(1, tl + 1);
  }

  // Combine halves (partials directly addable: no-max softmax) + epilogue.
  // FULLY UNROLLED (rule #20): qb must be compile-time so o[qb]/ol[qb] stay
  // in registers — R6's `unroll 1` here was the 565MB-scratch regression.
  int b = bh >> 4, h = bh & 15;
#pragma unroll
  for (int qb = 0; qb < 4; ++qb) {
    if (half) {
#pragma unroll
      for (int d = 0; d < 4; ++d)
#pragma unroll
        for (int r = 0; r < 4; ++r) cmb[wq][lane][d * 4 + r] = o[qb][d][r];
#pragma unroll
      for (int r = 0; r < 4; ++r) cmb[wq][lane][16 + r] = ol[qb][r];
    }
    __syncthreads();
    if (!half) {
      float linv[4];
#pragma unroll
      for (int r = 0; r < 4; ++r)
        linv[r] = __builtin_amdgcn_rcpf(ol[qb][r] + cmb[wq][lane][16 + r]);
#pragma unroll
      for (int d = 0; d < 4; ++d)
#pragma unroll
        for (int r = 0; r < 4; ++r) {
          float val = (o[qb][d][r] + cmb[wq][lane][d * 4 + r]) * linv[r];
          size_t row = (size_t)b * SS + q0 + wq * 64 + qb * 16 + g * 4 + r;
          ctx[row * DMODEL + h * 64 + d * 16 + lr] = f2bf(val);
        }
    }
    __syncthreads();
  }
}

// ---------------------------------------------------------------------------
// out[4096,1024] fp32 = ctx_bf16[4096,1024] @ Wb^T   (B^T-layout GEMM)
// 128x128 tile, BK=64, 4 waves of 64x64, global_load_lds staging (2-phase
// dbuf, pre-swizzled source, swizzled b128 reads).
// ---------------------------------------------------------------------------
__global__ void __launch_bounds__(256)
proj_gemm(const ushort_t* __restrict__ A, const ushort_t* __restrict__ Bw,
          float* __restrict__ out) {
  __shared__ ushort_t At[2][128][64];
  __shared__ ushort_t Bt[2][128][64];
  int m0 = blockIdx.x * 128, n0 = blockIdx.y * 128;
  int t = threadIdx.x;
  int wid = t >> 6, lane = t & 63;
  int wr = wid >> 1, wc = wid & 1;
  int g = lane >> 4, lr = lane & 15;
  int rsub = lane >> 3, ch = (lane & 7) ^ rsub;
  const f32x4 vzero = {0.f, 0.f, 0.f, 0.f};
  f32x4 acc[4][4];
#pragma unroll
  for (int m = 0; m < 4; ++m)
#pragma unroll
    for (int n = 0; n < 4; ++n) acc[m][n] = vzero;

  auto stage = [&](int buf, int k0) {
#pragma unroll
    for (int j = 0; j < 4; ++j) {
      int i = j * 4 + wid;  // 16 row-groups of 8 rows
      gload16(A + (size_t)(m0 + i * 8 + rsub) * DMODEL + k0 + ch * 8, &At[buf][i * 8][0]);
      gload16(Bw + (size_t)(n0 + i * 8 + rsub) * DMODEL + k0 + ch * 8, &Bt[buf][i * 8][0]);
    }
  };

  const int NTK = DMODEL / 64;  // 16
  auto step = [&](int cur, int kt) {
    if (kt + 1 < NTK) stage(cur ^ 1, (kt + 1) * 64);
#pragma unroll
    for (int kk = 0; kk < 2; ++kk) {
      bf16x8 af[4], bf[4];
#pragma unroll
      for (int m = 0; m < 4; ++m)
        af[m] = *(const bf16x8*)&At[cur][wr * 64 + m * 16 + lr]
                                      [((kk * 4 + g) ^ (lr & 7)) * 8];
#pragma unroll
      for (int n = 0; n < 4; ++n)
        bf[n] = *(const bf16x8*)&Bt[cur][wc * 64 + n * 16 + lr]
                                      [((kk * 4 + g) ^ (lr & 7)) * 8];
#pragma unroll
      for (int m = 0; m < 4; ++m)
#pragma unroll
        for (int n = 0; n < 4; ++n)
          acc[m][n] = __builtin_amdgcn_mfma_f32_16x16x32_bf16(af[m], bf[n], acc[m][n], 0, 0, 0);
    }
    __syncthreads();
  };

  stage(0, 0);
  __syncthreads();
#pragma unroll 1
  for (int kt = 0; kt < NTK; kt += 2) {
    step(0, kt);
    step(1, kt + 1);
  }
#pragma unroll
  for (int m = 0; m < 4; ++m)
#pragma unroll
    for (int n = 0; n < 4; ++n)
#pragma unroll
      for (int r = 0; r < 4; ++r)
        out[(size_t)(m0 + wr * 64 + m * 16 + g * 4 + r) * DMODEL +
            n0 + wc * 64 + n * 16 + lr] = acc[m][n][r];
}

extern "C" void kernel_launch(void* const* d_in, const int* in_sizes, int n_in,
                              void* d_out, int out_size, void* d_ws, size_t ws_size,
                              hipStream_t stream) {
  const float* q = (const float*)d_in[0];
  const float* k = (const float*)d_in[1];
  const float* v = (const float*)d_in[2];
  const float* w = (const float*)d_in[3];
  float* out = (float*)d_out;

  size_t nqk = (size_t)BB * HH * SS * 64;  // 4,194,304 elems per tensor
  ushort_t* Qh = (ushort_t*)d_ws;
  ushort_t* Kh = Qh + nqk;
  ushort_t* Vt = Kh + nqk;
  ushort_t* ctx = Vt + nqk;
  ushort_t* Wb = ctx + (size_t)BB * SS * DMODEL;
  size_t need = (4 * nqk + (size_t)DMODEL * DMODEL) * sizeof(ushort_t);  // ~34 MB
  if (ws_size < need) return;

  conv_qkv<<<dim3(SS / 64, BB * HH), 256, 0, stream>>>(q, k, v, Qh, Kh, Vt);
  conv_w<<<(DMODEL * DMODEL / 8) / 256, 256, 0, stream>>>(w, Wb);
  attn_fwd<<<dim3(SS / 256, BB * HH), 512, 0, stream>>>(Qh, Kh, Vt, ctx);
  proj_gemm<<<dim3((BB * SS) / 128, DMODEL / 128), 256, 0, stream>>>(ctx, Wb, out);
}

// Round 10
// 71.433 us; speedup vs baseline: 2.0985x; 1.0767x over previous
//
#include <hip/hip_runtime.h>

#define BB 2
#define HH 16
#define SS 2048
#define DMODEL 1024

typedef unsigned short ushort_t;
typedef short bf16x8 __attribute__((ext_vector_type(8)));   // 8 bf16 = 4 VGPR
typedef float f32x4 __attribute__((ext_vector_type(4)));

__device__ __forceinline__ unsigned short f2bf(float f) {
  union { float f; unsigned int u; } x; x.f = f;
  unsigned int u = x.u;
  return (unsigned short)((u + 0x7fffu + ((u >> 16) & 1u)) >> 16);  // RNE
}
__device__ __forceinline__ unsigned int pack2(float a, float b) {
  return (unsigned int)f2bf(a) | ((unsigned int)f2bf(b) << 16);
}
// 2 f32 -> packed 2x bf16 in one instruction (gfx950; no builtin, T12 recipe)
__device__ __forceinline__ unsigned int cvtpk(float lo, float hi) {
  unsigned int r;
  asm("v_cvt_pk_bf16_f32 %0, %1, %2" : "=v"(r) : "v"(lo), "v"(hi));
  return r;
}
// async global->LDS, 16B per lane; LDS dest is wave-uniform base + lane*16
__device__ __forceinline__ void gload16(const ushort_t* g, ushort_t* l) {
  __builtin_amdgcn_global_load_lds(
      (const __attribute__((address_space(1))) void*)g,
      (__attribute__((address_space(3))) void*)l, 16, 0, 0);
}

// ---------------------------------------------------------------------------
// R9: Q dropped (attn reads fp32 Q directly; softmax scale folded into K).
// fp32 K,V [B,S,H*64] -> bf16 Kh (pre-scaled by log2(e)/8) [B,H,S,64];
// V -> Vt [B,H,64,S] with per-64-tile k-permutation matching attn's in-lane
// P layout (swapped-QK): Vt[d][64t + pi(m)] = V[64t + m][d],
// pi(c*16+g*4+r) = (c>>1)*32 + g*8 + (c&1)*4 + r.
// ---------------------------------------------------------------------------
__global__ void __launch_bounds__(256)
conv_kv(const float* __restrict__ k, const float* __restrict__ v,
        ushort_t* __restrict__ Kh, ushort_t* __restrict__ Vt) {
  const float c_sc = 0.18033688011112042f;  // log2(e)/sqrt(64): folded into K
  __shared__ float vlds[64][65];  // +1 pad: conflict-free column reads
  int bh = blockIdx.y;
  int b = bh >> 4, h = bh & 15;
  int s0 = blockIdx.x * 64;
  int t = threadIdx.x;
#pragma unroll
  for (int j = 0; j < 4; ++j) {
    int idx = t + j * 256;
    int r = idx >> 4, c4 = idx & 15;  // 64 s-rows x 16 float4 of the 64-wide head slice
    size_t in_off = ((size_t)(b * SS + s0 + r)) * DMODEL + h * 64 + c4 * 4;
    float4 ka = *(const float4*)(k + in_off);
    float4 va = *(const float4*)(v + in_off);
    size_t out_off = ((size_t)bh * SS + s0 + r) * 64 + c4 * 4;
    *(uint2*)(Kh + out_off) = make_uint2(pack2(ka.x * c_sc, ka.y * c_sc),
                                         pack2(ka.z * c_sc, ka.w * c_sc));
    vlds[r][c4 * 4 + 0] = va.x;
    vlds[r][c4 * 4 + 1] = va.y;
    vlds[r][c4 * 4 + 2] = va.z;
    vlds[r][c4 * 4 + 3] = va.w;
  }
  __syncthreads();
#pragma unroll
  for (int j = 0; j < 4; ++j) {
    int idx = t + j * 256;
    int d = idx >> 4, u = idx & 15;  // 64 d-rows x 16 chunks of 4 permuted-k
    // chunk u covers positions u*4..u*4+3  <-  orig rows m0..m0+3,
    // m0 = c*16 + g*4 with c = (u>>3)*2 + (u&1), g = (u>>1)&3.
    int c = ((u >> 3) << 1) | (u & 1);
    int g = (u >> 1) & 3;
    int m0 = c * 16 + g * 4;
    size_t voff = ((size_t)bh * 64 + d) * SS + s0 + u * 4;
    *(uint2*)(Vt + voff) =
        make_uint2(pack2(vlds[m0 + 0][d], vlds[m0 + 1][d]),
                   pack2(vlds[m0 + 2][d], vlds[m0 + 3][d]));
  }
}

// fp32 [1024,1024] -> bf16 same layout (rows of W == B^T-GEMM operand rows)
__global__ void __launch_bounds__(256)
conv_w(const float* __restrict__ w, ushort_t* __restrict__ wb) {
  int i = blockIdx.x * 256 + threadIdx.x;  // one thread per 8 elements
  float4 a = *(const float4*)(w + (size_t)i * 8);
  float4 b = *(const float4*)(w + (size_t)i * 8 + 4);
  uint4 o;
  o.x = pack2(a.x, a.y);
  o.y = pack2(a.z, a.w);
  o.z = pack2(b.x, b.y);
  o.w = pack2(b.z, b.w);
  *(uint4*)(wb + (size_t)i * 8) = o;
}

// ---------------------------------------------------------------------------
// Flash attention fwd, no-max online softmax. In-block KV-split:
// 512 threads = 8 waves; q-tile 256 (64 rows/wave); waves 0-3 process kv
// tiles 0-15, waves 4-7 tiles 16-31 (each half has its own dbuf'd K/V LDS).
// R9: fp32 Q loaded directly (one-time cvtpk; scale pre-folded into Kh) —
// conv no longer touches Q. Combine epilogue: single barrier (write all 4 qb,
// sync once, read all) — was 8 barriers. Accumulator indices all compile-time
// (rule #20 — R6's runtime-qb epilogue was a 565MB scratch regression).
// ---------------------------------------------------------------------------
__global__ void __launch_bounds__(512, 1)
attn_fwd(const float* __restrict__ Qsrc, const ushort_t* __restrict__ Kh,
         const ushort_t* __restrict__ Vt, ushort_t* __restrict__ ctx) {
  __shared__ ushort_t K_lds[2][2][64][64];  // [half][dbuf], 16 KB per half
  __shared__ ushort_t V_lds[2][2][64][64];
  __shared__ __align__(16) float cmb[4][64][84];  // 84-dword stride: gcd(84/4,32)=... float4 lanes stride 336B, conflict-light; 86KB
  int bh = blockIdx.y;
  int b = bh >> 4, h = bh & 15;
  int q0 = blockIdx.x * 256;
  int tid = threadIdx.x;
  int wid = tid >> 6;
  int half = wid >> 2;   // kv half: 0 -> tiles 0-15, 1 -> tiles 16-31
  int wq = wid & 3;      // q-row group within the half
  int lane = tid & 63;
  int g = lane >> 4, lr = lane & 15;
  int rsub = lane >> 3, ch = (lane & 7) ^ rsub;  // stage: row-in-8 / swizzled chunk

  const ushort_t* Kp = Kh + (size_t)bh * SS * 64;
  const ushort_t* Vp = Vt + (size_t)bh * 64 * SS;

  ushort_t (*Kl)[64][64] = K_lds[half];  // this half's dbuf pair
  ushort_t (*Vl)[64][64] = V_lds[half];
  const int kvbase = half * (SS / 2);

  // Q fragments: load fp32 direct, convert in-register (scale lives in Kh).
  // B-operand of mfma(K,Q): B[d][q]=Q[q][d].
  bf16x8 qf[4][2];
#pragma unroll
  for (int qb = 0; qb < 4; ++qb) {
    int row = q0 + wq * 64 + qb * 16 + lr;
    const float* qr = Qsrc + ((size_t)(b * SS + row)) * DMODEL + h * 64;
#pragma unroll
    for (int kk = 0; kk < 2; ++kk) {
      float4 x = *(const float4*)(qr + kk * 32 + g * 8);
      float4 y = *(const float4*)(qr + kk * 32 + g * 8 + 4);
      uint4 wv;
      wv.x = cvtpk(x.x, x.y);
      wv.y = cvtpk(x.z, x.w);
      wv.z = cvtpk(y.x, y.y);
      wv.w = cvtpk(y.z, y.w);
      qf[qb][kk] = *(bf16x8*)&wv;
    }
  }

  const f32x4 vzero = {0.f, 0.f, 0.f, 0.f};
  const short ob = (short)0x3F80;  // bf16 1.0
  const bf16x8 ones = {ob, ob, ob, ob, ob, ob, ob, ob};
  f32x4 o[4][4];
  f32x4 ol[4];  // l via mfma(P, ones): row=g*4+r=q, all cols equal
#pragma unroll
  for (int qb = 0; qb < 4; ++qb) {
    ol[qb] = vzero;
#pragma unroll
    for (int d = 0; d < 4; ++d) o[qb][d] = vzero;
  }

  // Stage one 64-kv tile for this half (4 waves x 4 gload16).
  // Pre-swizzled source: LDS[row][c] = G[row][c ^ (row&7)].
  auto stage = [&](int buf, int kv) {
#pragma unroll
    for (int j = 0; j < 2; ++j) {
      int i = j * 4 + wq;
      gload16(Kp + (size_t)(kv + i * 8 + rsub) * 64 + ch * 8, &Kl[buf][i * 8][0]);
      gload16(Vp + (size_t)(i * 8 + rsub) * SS + kv + ch * 8, &Vl[buf][i * 8][0]);
    }
  };

  const int NTH = SS / 128;  // 16 tiles per half
  auto tile = [&](int cur, int tl) {  // cur LITERAL at each call site
    if (tl + 1 < NTH) stage(cur ^ 1, kvbase + (tl + 1) * 64);

    // K/V fragments (swizzled read): logical [c*16+lr][kk*32+g*8..+8)
    bf16x8 kf[4][2], vf[4][2];
#pragma unroll
    for (int c = 0; c < 4; ++c)
#pragma unroll
      for (int kk = 0; kk < 2; ++kk) {
        kf[c][kk] = *(const bf16x8*)&Kl[cur][c * 16 + lr]
                                       [((kk * 4 + g) ^ (lr & 7)) * 8];
        vf[c][kk] = *(const bf16x8*)&Vl[cur][c * 16 + lr]
                                       [((kk * 4 + g) ^ (lr & 7)) * 8];
      }

#pragma unroll
    for (int qb = 0; qb < 4; ++qb) {
      // S^T = K·Q^T: lane holds s[c][r] = S[k=c*16+g*4+r][q=qb*16+lr]
      f32x4 s[4];
      __builtin_amdgcn_s_setprio(1);
#pragma unroll
      for (int c = 0; c < 4; ++c) {
        s[c] = __builtin_amdgcn_mfma_f32_16x16x32_bf16(kf[c][0], qf[qb][0], vzero, 0, 0, 0);
        s[c] = __builtin_amdgcn_mfma_f32_16x16x32_bf16(kf[c][1], qf[qb][1], s[c], 0, 0, 0);
      }
      __builtin_amdgcn_s_setprio(0);
      // exp (K pre-scaled) + pack to PV A-fragments.
      float p[4][4];
#pragma unroll
      for (int c = 0; c < 4; ++c)
#pragma unroll
        for (int r = 0; r < 4; ++r) p[c][r] = __builtin_amdgcn_exp2f(s[c][r]);
      // pf[kk] elem j: (c,r) = (kk*2+(j>>2), j&3)  [pi-permutation, V matches]
      bf16x8 pf[2];
#pragma unroll
      for (int kk = 0; kk < 2; ++kk) {
        uint4 w;
        w.x = cvtpk(p[kk * 2][0], p[kk * 2][1]);
        w.y = cvtpk(p[kk * 2][2], p[kk * 2][3]);
        w.z = cvtpk(p[kk * 2 + 1][0], p[kk * 2 + 1][1]);
        w.w = cvtpk(p[kk * 2 + 1][2], p[kk * 2 + 1][3]);
        pf[kk] = *(bf16x8*)&w;
      }
      // PV + l: o += P·V_perm ; ol += P·1  (same C-layout as o)
      __builtin_amdgcn_s_setprio(1);
      ol[qb] = __builtin_amdgcn_mfma_f32_16x16x32_bf16(pf[0], ones, ol[qb], 0, 0, 0);
      ol[qb] = __builtin_amdgcn_mfma_f32_16x16x32_bf16(pf[1], ones, ol[qb], 0, 0, 0);
#pragma unroll
      for (int d = 0; d < 4; ++d) {
        o[qb][d] = __builtin_amdgcn_mfma_f32_16x16x32_bf16(pf[0], vf[d][0], o[qb][d], 0, 0, 0);
        o[qb][d] = __builtin_amdgcn_mfma_f32_16x16x32_bf16(pf[1], vf[d][1], o[qb][d], 0, 0, 0);
      }
      __builtin_amdgcn_s_setprio(0);
    }
    // both halves: staged buf drained at the barrier (vmcnt 0 before s_barrier)
    __syncthreads();
  };

  stage(0, kvbase);
  __syncthreads();  // buf0 ready for both halves
#pragma unroll 1
  for (int tl = 0; tl < NTH; tl += 2) {
    tile(0, tl);      // literal buffer indices: ds addrs = base + imm offset
    tile(1, tl + 1);
  }

  // Combine halves (no-max softmax: partials add directly). Single barrier:
  // half-1 writes all 4 qb (20 f32/qb/lane, float4-aligned stride 84), sync,
  // half-0 reads all. All o/ol indices compile-time (rule #20).
  if (half) {
#pragma unroll
    for (int qb = 0; qb < 4; ++qb) {
#pragma unroll
      for (int d = 0; d < 4; ++d)
        *(float4*)&cmb[wq][lane][qb * 20 + d * 4] = *(float4*)&o[qb][d];
      *(float4*)&cmb[wq][lane][qb * 20 + 16] = *(float4*)&ol[qb];
    }
  }
  __syncthreads();
  if (!half) {
#pragma unroll
    for (int qb = 0; qb < 4; ++qb) {
      float4 lo = *(float4*)&cmb[wq][lane][qb * 20 + 16];
      float linv[4];
      linv[0] = __builtin_amdgcn_rcpf(ol[qb][0] + lo.x);
      linv[1] = __builtin_amdgcn_rcpf(ol[qb][1] + lo.y);
      linv[2] = __builtin_amdgcn_rcpf(ol[qb][2] + lo.z);
      linv[3] = __builtin_amdgcn_rcpf(ol[qb][3] + lo.w);
#pragma unroll
      for (int d = 0; d < 4; ++d) {
        float4 oo = *(float4*)&cmb[wq][lane][qb * 20 + d * 4];
#pragma unroll
        for (int r = 0; r < 4; ++r) {
          float other = (r == 0) ? oo.x : (r == 1) ? oo.y : (r == 2) ? oo.z : oo.w;
          float val = (o[qb][d][r] + other) * linv[r];
          size_t row = (size_t)b * SS + q0 + wq * 64 + qb * 16 + g * 4 + r;
          ctx[row * DMODEL + h * 64 + d * 16 + lr] = f2bf(val);
        }
      }
    }
  }
}

// ---------------------------------------------------------------------------
// out[4096,1024] fp32 = ctx_bf16[4096,1024] @ Wb^T   (B^T-layout GEMM)
// R9: 64x128 tile (grid 64x8=512 = 2 blocks/CU -> 2 waves/SIMD; the old
// 128x128 grid-256 config was 1 wave/SIMD, latency-exposed). 4 waves of
// 32x64 (2x4 frags); LDS 48KB; launch_bounds(256,2) caps VGPR at 128
// (live ~90, no spill expected — verify WRITE_SIZE).
// ---------------------------------------------------------------------------
__global__ void __launch_bounds__(256, 2)
proj_gemm(const ushort_t* __restrict__ A, const ushort_t* __restrict__ Bw,
          float* __restrict__ out) {
  __shared__ ushort_t At[2][64][64];
  __shared__ ushort_t Bt[2][128][64];
  int m0 = blockIdx.x * 64, n0 = blockIdx.y * 128;
  int t = threadIdx.x;
  int wid = t >> 6, lane = t & 63;
  int wr = wid >> 1, wc = wid & 1;
  int g = lane >> 4, lr = lane & 15;
  int rsub = lane >> 3, ch = (lane & 7) ^ rsub;
  const f32x4 vzero = {0.f, 0.f, 0.f, 0.f};
  f32x4 acc[2][4];
#pragma unroll
  for (int m = 0; m < 2; ++m)
#pragma unroll
    for (int n = 0; n < 4; ++n) acc[m][n] = vzero;

  auto stage = [&](int buf, int k0) {
#pragma unroll
    for (int j = 0; j < 2; ++j) {
      int i = j * 4 + wid;  // 8 row-groups of 8 rows (A: 64 rows)
      gload16(A + (size_t)(m0 + i * 8 + rsub) * DMODEL + k0 + ch * 8, &At[buf][i * 8][0]);
    }
#pragma unroll
    for (int j = 0; j < 4; ++j) {
      int i = j * 4 + wid;  // 16 row-groups (B: 128 rows)
      gload16(Bw + (size_t)(n0 + i * 8 + rsub) * DMODEL + k0 + ch * 8, &Bt[buf][i * 8][0]);
    }
  };

  const int NTK = DMODEL / 64;  // 16
  auto step = [&](int cur, int kt) {
    if (kt + 1 < NTK) stage(cur ^ 1, (kt + 1) * 64);
#pragma unroll
    for (int kk = 0; kk < 2; ++kk) {
      bf16x8 af[2], bf[4];
#pragma unroll
      for (int m = 0; m < 2; ++m)
        af[m] = *(const bf16x8*)&At[cur][wr * 32 + m * 16 + lr]
                                      [((kk * 4 + g) ^ (lr & 7)) * 8];
#pragma unroll
      for (int n = 0; n < 4; ++n)
        bf[n] = *(const bf16x8*)&Bt[cur][wc * 64 + n * 16 + lr]
                                      [((kk * 4 + g) ^ (lr & 7)) * 8];
#pragma unroll
      for (int m = 0; m < 2; ++m)
#pragma unroll
        for (int n = 0; n < 4; ++n)
          acc[m][n] = __builtin_amdgcn_mfma_f32_16x16x32_bf16(af[m], bf[n], acc[m][n], 0, 0, 0);
    }
    __syncthreads();
  };

  stage(0, 0);
  __syncthreads();
#pragma unroll 1
  for (int kt = 0; kt < NTK; kt += 2) {
    step(0, kt);
    step(1, kt + 1);
  }
#pragma unroll
  for (int m = 0; m < 2; ++m)
#pragma unroll
    for (int n = 0; n < 4; ++n)
#pragma unroll
      for (int r = 0; r < 4; ++r)
        out[(size_t)(m0 + wr * 32 + m * 16 + g * 4 + r) * DMODEL +
            n0 + wc * 64 + n * 16 + lr] = acc[m][n][r];
}

extern "C" void kernel_launch(void* const* d_in, const int* in_sizes, int n_in,
                              void* d_out, int out_size, void* d_ws, size_t ws_size,
                              hipStream_t stream) {
  const float* q = (const float*)d_in[0];
  const float* k = (const float*)d_in[1];
  const float* v = (const float*)d_in[2];
  const float* w = (const float*)d_in[3];
  float* out = (float*)d_out;

  size_t nqk = (size_t)BB * HH * SS * 64;  // 4,194,304 elems per tensor
  ushort_t* Kh = (ushort_t*)d_ws;
  ushort_t* Vt = Kh + nqk;
  ushort_t* ctx = Vt + nqk;
  ushort_t* Wb = ctx + (size_t)BB * SS * DMODEL;
  size_t need = (3 * nqk + (size_t)DMODEL * DMODEL) * sizeof(ushort_t);  // ~27 MB
  if (ws_size < need) return;

  conv_kv<<<dim3(SS / 64, BB * HH), 256, 0, stream>>>(k, v, Kh, Vt);
  conv_w<<<(DMODEL * DMODEL / 8) / 256, 256, 0, stream>>>(w, Wb);
  attn_fwd<<<dim3(SS / 256, BB * HH), 512, 0, stream>>>(q, Kh, Vt, ctx);
  proj_gemm<<<dim3((BB * SS) / 64, DMODEL / 128), 256, 0, stream>>>(ctx, Wb, out);
}

// Round 11
// 70.346 us; speedup vs baseline: 2.1309x; 1.0155x over previous
//
#include <hip/hip_runtime.h>

#define BB 2
#define HH 16
#define SS 2048
#define DMODEL 1024

typedef unsigned short ushort_t;
typedef short bf16x8 __attribute__((ext_vector_type(8)));   // 8 bf16 = 4 VGPR
typedef float f32x4 __attribute__((ext_vector_type(4)));

__device__ __forceinline__ unsigned short f2bf(float f) {
  union { float f; unsigned int u; } x; x.f = f;
  unsigned int u = x.u;
  return (unsigned short)((u + 0x7fffu + ((u >> 16) & 1u)) >> 16);  // RNE
}
__device__ __forceinline__ unsigned int pack2(float a, float b) {
  return (unsigned int)f2bf(a) | ((unsigned int)f2bf(b) << 16);
}
// 2 f32 -> packed 2x bf16 in one instruction (gfx950; no builtin, T12 recipe)
__device__ __forceinline__ unsigned int cvtpk(float lo, float hi) {
  unsigned int r;
  asm("v_cvt_pk_bf16_f32 %0, %1, %2" : "=v"(r) : "v"(lo), "v"(hi));
  return r;
}
// async global->LDS, 16B per lane; LDS dest is wave-uniform base + lane*16
__device__ __forceinline__ void gload16(const ushort_t* g, ushort_t* l) {
  __builtin_amdgcn_global_load_lds(
      (const __attribute__((address_space(1))) void*)g,
      (__attribute__((address_space(3))) void*)l, 16, 0, 0);
}

// ---------------------------------------------------------------------------
// R10: conv_kv + conv_w merged into one dispatch (1536 blocks: 1024 KV + 512 W)
// — saves a launch gap; W-blocks backfill CUs during KV conversion.
// fp32 K,V [B,S,H*64] -> bf16 Kh (pre-scaled by log2(e)/8) [B,H,S,64];
// V -> Vt [B,H,64,S] with per-64-tile k-permutation matching attn's in-lane
// P layout (swapped-QK): Vt[d][64t + pi(m)] = V[64t + m][d],
// pi(c*16+g*4+r) = (c>>1)*32 + g*8 + (c&1)*4 + r.
// W fp32 [1024,1024] -> bf16 same layout.
// ---------------------------------------------------------------------------
__global__ void __launch_bounds__(256)
conv_fused(const float* __restrict__ k, const float* __restrict__ v,
           const float* __restrict__ w, ushort_t* __restrict__ Kh,
           ushort_t* __restrict__ Vt, ushort_t* __restrict__ wb) {
  int bid = blockIdx.x;
  int t = threadIdx.x;
  if (bid >= 1024) {  // ---- W part: 512 blocks, one thread per 8 elements
    int i = (bid - 1024) * 256 + t;
    float4 a = *(const float4*)(w + (size_t)i * 8);
    float4 bq = *(const float4*)(w + (size_t)i * 8 + 4);
    uint4 o;
    o.x = pack2(a.x, a.y);
    o.y = pack2(a.z, a.w);
    o.z = pack2(bq.x, bq.y);
    o.w = pack2(bq.z, bq.w);
    *(uint4*)(wb + (size_t)i * 8) = o;
    return;
  }
  // ---- KV part: 1024 blocks (32 s-blocks x 32 bh)
  const float c_sc = 0.18033688011112042f;  // log2(e)/sqrt(64): folded into K
  __shared__ float vlds[64][65];  // +1 pad: conflict-free column reads
  int bh = bid >> 5;
  int b = bh >> 4, h = bh & 15;
  int s0 = (bid & 31) * 64;
#pragma unroll
  for (int j = 0; j < 4; ++j) {
    int idx = t + j * 256;
    int r = idx >> 4, c4 = idx & 15;  // 64 s-rows x 16 float4 of the 64-wide head slice
    size_t in_off = ((size_t)(b * SS + s0 + r)) * DMODEL + h * 64 + c4 * 4;
    float4 ka = *(const float4*)(k + in_off);
    float4 va = *(const float4*)(v + in_off);
    size_t out_off = ((size_t)bh * SS + s0 + r) * 64 + c4 * 4;
    *(uint2*)(Kh + out_off) = make_uint2(pack2(ka.x * c_sc, ka.y * c_sc),
                                         pack2(ka.z * c_sc, ka.w * c_sc));
    vlds[r][c4 * 4 + 0] = va.x;
    vlds[r][c4 * 4 + 1] = va.y;
    vlds[r][c4 * 4 + 2] = va.z;
    vlds[r][c4 * 4 + 3] = va.w;
  }
  __syncthreads();
#pragma unroll
  for (int j = 0; j < 4; ++j) {
    int idx = t + j * 256;
    int d = idx >> 4, u = idx & 15;  // 64 d-rows x 16 chunks of 4 permuted-k
    // chunk u covers positions u*4..u*4+3  <-  orig rows m0..m0+3,
    // m0 = c*16 + g*4 with c = (u>>3)*2 + (u&1), g = (u>>1)&3.
    int c = ((u >> 3) << 1) | (u & 1);
    int g = (u >> 1) & 3;
    int m0 = c * 16 + g * 4;
    size_t voff = ((size_t)bh * 64 + d) * SS + s0 + u * 4;
    *(uint2*)(Vt + voff) =
        make_uint2(pack2(vlds[m0 + 0][d], vlds[m0 + 1][d]),
                   pack2(vlds[m0 + 2][d], vlds[m0 + 3][d]));
  }
}

// ---------------------------------------------------------------------------
// Flash attention fwd, no-max online softmax. In-block KV-split:
// 512 threads = 8 waves; q-tile 256 (64 rows/wave); waves 0-3 process kv
// tiles 0-15, waves 4-7 tiles 16-31 (each half has its own dbuf'd K/V LDS).
// fp32 Q loaded directly (scale pre-folded into Kh). R10: stage(0) issued
// BEFORE the Q loads — K/V gload_lds owns the critical path for tile 0; the
// 32 Q dwordx4 + cvtpk fill its latency shadow. Combine epilogue: single
// barrier. Accumulator indices all compile-time (rule #20).
// ---------------------------------------------------------------------------
__global__ void __launch_bounds__(512, 1)
attn_fwd(const float* __restrict__ Qsrc, const ushort_t* __restrict__ Kh,
         const ushort_t* __restrict__ Vt, ushort_t* __restrict__ ctx) {
  __shared__ ushort_t K_lds[2][2][64][64];  // [half][dbuf], 16 KB per half
  __shared__ ushort_t V_lds[2][2][64][64];
  __shared__ __align__(16) float cmb[4][64][84];
  int bh = blockIdx.y;
  int b = bh >> 4, h = bh & 15;
  int q0 = blockIdx.x * 256;
  int tid = threadIdx.x;
  int wid = tid >> 6;
  int half = wid >> 2;   // kv half: 0 -> tiles 0-15, 1 -> tiles 16-31
  int wq = wid & 3;      // q-row group within the half
  int lane = tid & 63;
  int g = lane >> 4, lr = lane & 15;
  int rsub = lane >> 3, ch = (lane & 7) ^ rsub;  // stage: row-in-8 / swizzled chunk

  const ushort_t* Kp = Kh + (size_t)bh * SS * 64;
  const ushort_t* Vp = Vt + (size_t)bh * 64 * SS;

  ushort_t (*Kl)[64][64] = K_lds[half];  // this half's dbuf pair
  ushort_t (*Vl)[64][64] = V_lds[half];
  const int kvbase = half * (SS / 2);

  // Stage one 64-kv tile for this half (4 waves x 4 gload16).
  // Pre-swizzled source: LDS[row][c] = G[row][c ^ (row&7)].
  auto stage = [&](int buf, int kv) {
#pragma unroll
    for (int j = 0; j < 2; ++j) {
      int i = j * 4 + wq;
      gload16(Kp + (size_t)(kv + i * 8 + rsub) * 64 + ch * 8, &Kl[buf][i * 8][0]);
      gload16(Vp + (size_t)(i * 8 + rsub) * SS + kv + ch * 8, &Vl[buf][i * 8][0]);
    }
  };

  stage(0, kvbase);  // issue K/V first: tile-0 critical path

  // Q fragments: load fp32 direct, convert in-register (scale lives in Kh).
  // B-operand of mfma(K,Q): B[d][q]=Q[q][d]. Fills stage(0)'s latency shadow.
  bf16x8 qf[4][2];
#pragma unroll
  for (int qb = 0; qb < 4; ++qb) {
    int row = q0 + wq * 64 + qb * 16 + lr;
    const float* qr = Qsrc + ((size_t)(b * SS + row)) * DMODEL + h * 64;
#pragma unroll
    for (int kk = 0; kk < 2; ++kk) {
      float4 x = *(const float4*)(qr + kk * 32 + g * 8);
      float4 y = *(const float4*)(qr + kk * 32 + g * 8 + 4);
      uint4 wv;
      wv.x = cvtpk(x.x, x.y);
      wv.y = cvtpk(x.z, x.w);
      wv.z = cvtpk(y.x, y.y);
      wv.w = cvtpk(y.z, y.w);
      qf[qb][kk] = *(bf16x8*)&wv;
    }
  }

  const f32x4 vzero = {0.f, 0.f, 0.f, 0.f};
  const short ob = (short)0x3F80;  // bf16 1.0
  const bf16x8 ones = {ob, ob, ob, ob, ob, ob, ob, ob};
  f32x4 o[4][4];
  f32x4 ol[4];  // l via mfma(P, ones): row=g*4+r=q, all cols equal
#pragma unroll
  for (int qb = 0; qb < 4; ++qb) {
    ol[qb] = vzero;
#pragma unroll
    for (int d = 0; d < 4; ++d) o[qb][d] = vzero;
  }

  const int NTH = SS / 128;  // 16 tiles per half
  auto tile = [&](int cur, int tl) {  // cur LITERAL at each call site
    if (tl + 1 < NTH) stage(cur ^ 1, kvbase + (tl + 1) * 64);

    // K/V fragments (swizzled read): logical [c*16+lr][kk*32+g*8..+8)
    bf16x8 kf[4][2], vf[4][2];
#pragma unroll
    for (int c = 0; c < 4; ++c)
#pragma unroll
      for (int kk = 0; kk < 2; ++kk) {
        kf[c][kk] = *(const bf16x8*)&Kl[cur][c * 16 + lr]
                                       [((kk * 4 + g) ^ (lr & 7)) * 8];
        vf[c][kk] = *(const bf16x8*)&Vl[cur][c * 16 + lr]
                                       [((kk * 4 + g) ^ (lr & 7)) * 8];
      }

#pragma unroll
    for (int qb = 0; qb < 4; ++qb) {
      // S^T = K·Q^T: lane holds s[c][r] = S[k=c*16+g*4+r][q=qb*16+lr]
      f32x4 s[4];
      __builtin_amdgcn_s_setprio(1);
#pragma unroll
      for (int c = 0; c < 4; ++c) {
        s[c] = __builtin_amdgcn_mfma_f32_16x16x32_bf16(kf[c][0], qf[qb][0], vzero, 0, 0, 0);
        s[c] = __builtin_amdgcn_mfma_f32_16x16x32_bf16(kf[c][1], qf[qb][1], s[c], 0, 0, 0);
      }
      __builtin_amdgcn_s_setprio(0);
      // exp (K pre-scaled) + pack to PV A-fragments.
      float p[4][4];
#pragma unroll
      for (int c = 0; c < 4; ++c)
#pragma unroll
        for (int r = 0; r < 4; ++r) p[c][r] = __builtin_amdgcn_exp2f(s[c][r]);
      // pf[kk] elem j: (c,r) = (kk*2+(j>>2), j&3)  [pi-permutation, V matches]
      bf16x8 pf[2];
#pragma unroll
      for (int kk = 0; kk < 2; ++kk) {
        uint4 w;
        w.x = cvtpk(p[kk * 2][0], p[kk * 2][1]);
        w.y = cvtpk(p[kk * 2][2], p[kk * 2][3]);
        w.z = cvtpk(p[kk * 2 + 1][0], p[kk * 2 + 1][1]);
        w.w = cvtpk(p[kk * 2 + 1][2], p[kk * 2 + 1][3]);
        pf[kk] = *(bf16x8*)&w;
      }
      // PV + l: o += P·V_perm ; ol += P·1  (same C-layout as o)
      __builtin_amdgcn_s_setprio(1);
      ol[qb] = __builtin_amdgcn_mfma_f32_16x16x32_bf16(pf[0], ones, ol[qb], 0, 0, 0);
      ol[qb] = __builtin_amdgcn_mfma_f32_16x16x32_bf16(pf[1], ones, ol[qb], 0, 0, 0);
#pragma unroll
      for (int d = 0; d < 4; ++d) {
        o[qb][d] = __builtin_amdgcn_mfma_f32_16x16x32_bf16(pf[0], vf[d][0], o[qb][d], 0, 0, 0);
        o[qb][d] = __builtin_amdgcn_mfma_f32_16x16x32_bf16(pf[1], vf[d][1], o[qb][d], 0, 0, 0);
      }
      __builtin_amdgcn_s_setprio(0);
    }
    // both halves: staged buf drained at the barrier (vmcnt 0 before s_barrier)
    __syncthreads();
  };

  __syncthreads();  // buf0 ready for both halves (drains stage(0) + Q loads)
#pragma unroll 1
  for (int tl = 0; tl < NTH; tl += 2) {
    tile(0, tl);      // literal buffer indices: ds addrs = base + imm offset
    tile(1, tl + 1);
  }

  // Combine halves (no-max softmax: partials add directly). Single barrier:
  // half-1 writes all 4 qb (20 f32/qb/lane, float4 stride 84), sync,
  // half-0 reads all. All o/ol indices compile-time (rule #20).
  if (half) {
#pragma unroll
    for (int qb = 0; qb < 4; ++qb) {
#pragma unroll
      for (int d = 0; d < 4; ++d)
        *(float4*)&cmb[wq][lane][qb * 20 + d * 4] = *(float4*)&o[qb][d];
      *(float4*)&cmb[wq][lane][qb * 20 + 16] = *(float4*)&ol[qb];
    }
  }
  __syncthreads();
  if (!half) {
#pragma unroll
    for (int qb = 0; qb < 4; ++qb) {
      float4 lo = *(float4*)&cmb[wq][lane][qb * 20 + 16];
      float linv[4];
      linv[0] = __builtin_amdgcn_rcpf(ol[qb][0] + lo.x);
      linv[1] = __builtin_amdgcn_rcpf(ol[qb][1] + lo.y);
      linv[2] = __builtin_amdgcn_rcpf(ol[qb][2] + lo.z);
      linv[3] = __builtin_amdgcn_rcpf(ol[qb][3] + lo.w);
#pragma unroll
      for (int d = 0; d < 4; ++d) {
        float4 oo = *(float4*)&cmb[wq][lane][qb * 20 + d * 4];
#pragma unroll
        for (int r = 0; r < 4; ++r) {
          float other = (r == 0) ? oo.x : (r == 1) ? oo.y : (r == 2) ? oo.z : oo.w;
          float val = (o[qb][d][r] + other) * linv[r];
          size_t row = (size_t)b * SS + q0 + wq * 64 + qb * 16 + g * 4 + r;
          ctx[row * DMODEL + h * 64 + d * 16 + lr] = f2bf(val);
        }
      }
    }
  }
}

// ---------------------------------------------------------------------------
// out[4096,1024] fp32 = ctx_bf16[4096,1024] @ Wb^T   (B^T-layout GEMM)
// R10: 128x128 tile @ 512 threads (8 waves, 2x4 wave grid, acc[4][2]) —
// same 2 waves/SIMD as R9's 64x128 but HALF the blocks (grid 32x8=256) =>
// half the staging traffic, 2x MFMA per staged KB. LDS 64KB, 1 block/CU.
// ---------------------------------------------------------------------------
__global__ void __launch_bounds__(512, 1)
proj_gemm(const ushort_t* __restrict__ A, const ushort_t* __restrict__ Bw,
          float* __restrict__ out) {
  __shared__ ushort_t At[2][128][64];
  __shared__ ushort_t Bt[2][128][64];
  int m0 = blockIdx.x * 128, n0 = blockIdx.y * 128;
  int t = threadIdx.x;
  int wid = t >> 6, lane = t & 63;
  int wr = wid >> 2, wc = wid & 3;  // 2x4 wave grid: 64-row x 32-col tiles
  int g = lane >> 4, lr = lane & 15;
  int rsub = lane >> 3, ch = (lane & 7) ^ rsub;
  const f32x4 vzero = {0.f, 0.f, 0.f, 0.f};
  f32x4 acc[4][2];
#pragma unroll
  for (int m = 0; m < 4; ++m)
#pragma unroll
    for (int n = 0; n < 2; ++n) acc[m][n] = vzero;

  auto stage = [&](int buf, int k0) {
#pragma unroll
    for (int j = 0; j < 2; ++j) {
      int i = j * 8 + wid;  // 16 row-groups of 8 rows each for A and B
      gload16(A + (size_t)(m0 + i * 8 + rsub) * DMODEL + k0 + ch * 8, &At[buf][i * 8][0]);
      gload16(Bw + (size_t)(n0 + i * 8 + rsub) * DMODEL + k0 + ch * 8, &Bt[buf][i * 8][0]);
    }
  };

  const int NTK = DMODEL / 64;  // 16
  auto step = [&](int cur, int kt) {
    if (kt + 1 < NTK) stage(cur ^ 1, (kt + 1) * 64);
#pragma unroll
    for (int kk = 0; kk < 2; ++kk) {
      bf16x8 af[4], bf[2];
#pragma unroll
      for (int m = 0; m < 4; ++m)
        af[m] = *(const bf16x8*)&At[cur][wr * 64 + m * 16 + lr]
                                      [((kk * 4 + g) ^ (lr & 7)) * 8];
#pragma unroll
      for (int n = 0; n < 2; ++n)
        bf[n] = *(const bf16x8*)&Bt[cur][wc * 32 + n * 16 + lr]
                                      [((kk * 4 + g) ^ (lr & 7)) * 8];
#pragma unroll
      for (int m = 0; m < 4; ++m)
#pragma unroll
        for (int n = 0; n < 2; ++n)
          acc[m][n] = __builtin_amdgcn_mfma_f32_16x16x32_bf16(af[m], bf[n], acc[m][n], 0, 0, 0);
    }
    __syncthreads();
  };

  stage(0, 0);
  __syncthreads();
#pragma unroll 1
  for (int kt = 0; kt < NTK; kt += 2) {
    step(0, kt);
    step(1, kt + 1);
  }
#pragma unroll
  for (int m = 0; m < 4; ++m)
#pragma unroll
    for (int n = 0; n < 2; ++n)
#pragma unroll
      for (int r = 0; r < 4; ++r)
        out[(size_t)(m0 + wr * 64 + m * 16 + g * 4 + r) * DMODEL +
            n0 + wc * 32 + n * 16 + lr] = acc[m][n][r];
}

extern "C" void kernel_launch(void* const* d_in, const int* in_sizes, int n_in,
                              void* d_out, int out_size, void* d_ws, size_t ws_size,
                              hipStream_t stream) {
  const float* q = (const float*)d_in[0];
  const float* k = (const float*)d_in[1];
  const float* v = (const float*)d_in[2];
  const float* w = (const float*)d_in[3];
  float* out = (float*)d_out;

  size_t nqk = (size_t)BB * HH * SS * 64;  // 4,194,304 elems per tensor
  ushort_t* Kh = (ushort_t*)d_ws;
  ushort_t* Vt = Kh + nqk;
  ushort_t* ctx = Vt + nqk;
  ushort_t* Wb = ctx + (size_t)BB * SS * DMODEL;
  size_t need = (3 * nqk + (size_t)DMODEL * DMODEL) * sizeof(ushort_t);  // ~27 MB
  if (ws_size < need) return;

  conv_fused<<<1024 + 512, 256, 0, stream>>>(k, v, w, Kh, Vt, Wb);
  attn_fwd<<<dim3(SS / 256, BB * HH), 512, 0, stream>>>(q, Kh, Vt, ctx);
  proj_gemm<<<dim3((BB * SS) / 128, DMODEL / 128), 512, 0, stream>>>(ctx, Wb, out);
}

// Round 12
// 68.626 us; speedup vs baseline: 2.1843x; 1.0251x over previous
//
#include <hip/hip_runtime.h>

#define BB 2
#define HH 16
#define SS 2048
#define DMODEL 1024

typedef unsigned short ushort_t;
typedef short bf16x8 __attribute__((ext_vector_type(8)));   // 8 bf16 = 4 VGPR
typedef float f32x4 __attribute__((ext_vector_type(4)));

__device__ __forceinline__ unsigned short f2bf(float f) {
  union { float f; unsigned int u; } x; x.f = f;
  unsigned int u = x.u;
  return (unsigned short)((u + 0x7fffu + ((u >> 16) & 1u)) >> 16);  // RNE
}
__device__ __forceinline__ unsigned int pack2(float a, float b) {
  return (unsigned int)f2bf(a) | ((unsigned int)f2bf(b) << 16);
}
// 2 f32 -> packed 2x bf16 in one instruction (gfx950; no builtin, T12 recipe)
__device__ __forceinline__ unsigned int cvtpk(float lo, float hi) {
  unsigned int r;
  asm("v_cvt_pk_bf16_f32 %0, %1, %2" : "=v"(r) : "v"(lo), "v"(hi));
  return r;
}
// async global->LDS, 16B per lane; LDS dest is wave-uniform base + lane*16
__device__ __forceinline__ void gload16(const ushort_t* g, ushort_t* l) {
  __builtin_amdgcn_global_load_lds(
      (const __attribute__((address_space(1))) void*)g,
      (__attribute__((address_space(3))) void*)l, 16, 0, 0);
}

// ---------------------------------------------------------------------------
// conv_kv + conv_w in one dispatch (1536 blocks: 1024 KV + 512 W).
// fp32 K,V [B,S,H*64] -> bf16 Kh (pre-scaled by log2(e)/8) [B,H,S,64];
// V -> Vt [B,H,64,S] with per-64-tile k-permutation matching attn's in-lane
// P layout (swapped-QK): Vt[d][64t + pi(m)] = V[64t + m][d],
// pi(c*16+g*4+r) = (c>>1)*32 + g*8 + (c&1)*4 + r.
// W fp32 [1024,1024] -> bf16 same layout. Streaming, no reuse: no swizzle.
// ---------------------------------------------------------------------------
__global__ void __launch_bounds__(256)
conv_fused(const float* __restrict__ k, const float* __restrict__ v,
           const float* __restrict__ w, ushort_t* __restrict__ Kh,
           ushort_t* __restrict__ Vt, ushort_t* __restrict__ wb) {
  int bid = blockIdx.x;
  int t = threadIdx.x;
  if (bid >= 1024) {  // ---- W part: 512 blocks, one thread per 8 elements
    int i = (bid - 1024) * 256 + t;
    float4 a = *(const float4*)(w + (size_t)i * 8);
    float4 bq = *(const float4*)(w + (size_t)i * 8 + 4);
    uint4 o;
    o.x = pack2(a.x, a.y);
    o.y = pack2(a.z, a.w);
    o.z = pack2(bq.x, bq.y);
    o.w = pack2(bq.z, bq.w);
    *(uint4*)(wb + (size_t)i * 8) = o;
    return;
  }
  // ---- KV part: 1024 blocks (32 s-blocks x 32 bh)
  const float c_sc = 0.18033688011112042f;  // log2(e)/sqrt(64): folded into K
  __shared__ float vlds[64][65];  // +1 pad: conflict-free column reads
  int bh = bid >> 5;
  int b = bh >> 4, h = bh & 15;
  int s0 = (bid & 31) * 64;
#pragma unroll
  for (int j = 0; j < 4; ++j) {
    int idx = t + j * 256;
    int r = idx >> 4, c4 = idx & 15;  // 64 s-rows x 16 float4 of the 64-wide head slice
    size_t in_off = ((size_t)(b * SS + s0 + r)) * DMODEL + h * 64 + c4 * 4;
    float4 ka = *(const float4*)(k + in_off);
    float4 va = *(const float4*)(v + in_off);
    size_t out_off = ((size_t)bh * SS + s0 + r) * 64 + c4 * 4;
    *(uint2*)(Kh + out_off) = make_uint2(pack2(ka.x * c_sc, ka.y * c_sc),
                                         pack2(ka.z * c_sc, ka.w * c_sc));
    vlds[r][c4 * 4 + 0] = va.x;
    vlds[r][c4 * 4 + 1] = va.y;
    vlds[r][c4 * 4 + 2] = va.z;
    vlds[r][c4 * 4 + 3] = va.w;
  }
  __syncthreads();
#pragma unroll
  for (int j = 0; j < 4; ++j) {
    int idx = t + j * 256;
    int d = idx >> 4, u = idx & 15;  // 64 d-rows x 16 chunks of 4 permuted-k
    int c = ((u >> 3) << 1) | (u & 1);
    int g = (u >> 1) & 3;
    int m0 = c * 16 + g * 4;
    size_t voff = ((size_t)bh * 64 + d) * SS + s0 + u * 4;
    *(uint2*)(Vt + voff) =
        make_uint2(pack2(vlds[m0 + 0][d], vlds[m0 + 1][d]),
                   pack2(vlds[m0 + 2][d], vlds[m0 + 3][d]));
  }
}

// ---------------------------------------------------------------------------
// Flash attention fwd, no-max online softmax. In-block KV-split:
// 512 threads = 8 waves; q-tile 256 (64 rows/wave); waves 0-3 process kv
// tiles 0-15, waves 4-7 tiles 16-31 (each half has its own dbuf'd K/V LDS).
// R11: T1 XCD swizzle — 1D grid 256; XCD = bid&7 (round-robin dispatch);
// bh = (bid&7)*4 + ((bid>>3)&3), q0 = (bid>>5)*256 so each XCD owns 4 bh
// COMPLETE (all 8 q-blocks) -> K/V working set 2MB fits its private L2.
// R10's layout scattered the 8 sharers across 8 XCDs: FETCH showed 3.4x
// K/V refetch from HBM (73.8MB vs 34MB ideal). Correctness is mapping-
// independent (bijection checked: grid 256 % 8 == 0).
// ---------------------------------------------------------------------------
__global__ void __launch_bounds__(512, 1)
attn_fwd(const float* __restrict__ Qsrc, const ushort_t* __restrict__ Kh,
         const ushort_t* __restrict__ Vt, ushort_t* __restrict__ ctx) {
  __shared__ ushort_t K_lds[2][2][64][64];  // [half][dbuf], 16 KB per half
  __shared__ ushort_t V_lds[2][2][64][64];
  __shared__ __align__(16) float cmb[4][64][84];
  int bid = blockIdx.x;
  int bh = (bid & 7) * 4 + ((bid >> 3) & 3);  // XCD-resident bh group
  int q0 = (bid >> 5) * 256;
  int b = bh >> 4, h = bh & 15;
  int tid = threadIdx.x;
  int wid = tid >> 6;
  int half = wid >> 2;   // kv half: 0 -> tiles 0-15, 1 -> tiles 16-31
  int wq = wid & 3;      // q-row group within the half
  int lane = tid & 63;
  int g = lane >> 4, lr = lane & 15;
  int rsub = lane >> 3, ch = (lane & 7) ^ rsub;  // stage: row-in-8 / swizzled chunk

  const ushort_t* Kp = Kh + (size_t)bh * SS * 64;
  const ushort_t* Vp = Vt + (size_t)bh * 64 * SS;

  ushort_t (*Kl)[64][64] = K_lds[half];  // this half's dbuf pair
  ushort_t (*Vl)[64][64] = V_lds[half];
  const int kvbase = half * (SS / 2);

  // Stage one 64-kv tile for this half (4 waves x 4 gload16).
  // Pre-swizzled source: LDS[row][c] = G[row][c ^ (row&7)].
  auto stage = [&](int buf, int kv) {
#pragma unroll
    for (int j = 0; j < 2; ++j) {
      int i = j * 4 + wq;
      gload16(Kp + (size_t)(kv + i * 8 + rsub) * 64 + ch * 8, &Kl[buf][i * 8][0]);
      gload16(Vp + (size_t)(i * 8 + rsub) * SS + kv + ch * 8, &Vl[buf][i * 8][0]);
    }
  };

  stage(0, kvbase);  // issue K/V first: tile-0 critical path

  // Q fragments: load fp32 direct, convert in-register (scale lives in Kh).
  // B-operand of mfma(K,Q): B[d][q]=Q[q][d]. Fills stage(0)'s latency shadow.
  bf16x8 qf[4][2];
#pragma unroll
  for (int qb = 0; qb < 4; ++qb) {
    int row = q0 + wq * 64 + qb * 16 + lr;
    const float* qr = Qsrc + ((size_t)(b * SS + row)) * DMODEL + h * 64;
#pragma unroll
    for (int kk = 0; kk < 2; ++kk) {
      float4 x = *(const float4*)(qr + kk * 32 + g * 8);
      float4 y = *(const float4*)(qr + kk * 32 + g * 8 + 4);
      uint4 wv;
      wv.x = cvtpk(x.x, x.y);
      wv.y = cvtpk(x.z, x.w);
      wv.z = cvtpk(y.x, y.y);
      wv.w = cvtpk(y.z, y.w);
      qf[qb][kk] = *(bf16x8*)&wv;
    }
  }

  const f32x4 vzero = {0.f, 0.f, 0.f, 0.f};
  const short ob = (short)0x3F80;  // bf16 1.0
  const bf16x8 ones = {ob, ob, ob, ob, ob, ob, ob, ob};
  f32x4 o[4][4];
  f32x4 ol[4];  // l via mfma(P, ones): row=g*4+r=q, all cols equal
#pragma unroll
  for (int qb = 0; qb < 4; ++qb) {
    ol[qb] = vzero;
#pragma unroll
    for (int d = 0; d < 4; ++d) o[qb][d] = vzero;
  }

  const int NTH = SS / 128;  // 16 tiles per half
  auto tile = [&](int cur, int tl) {  // cur LITERAL at each call site
    if (tl + 1 < NTH) stage(cur ^ 1, kvbase + (tl + 1) * 64);

    // K/V fragments (swizzled read): logical [c*16+lr][kk*32+g*8..+8)
    bf16x8 kf[4][2], vf[4][2];
#pragma unroll
    for (int c = 0; c < 4; ++c)
#pragma unroll
      for (int kk = 0; kk < 2; ++kk) {
        kf[c][kk] = *(const bf16x8*)&Kl[cur][c * 16 + lr]
                                       [((kk * 4 + g) ^ (lr & 7)) * 8];
        vf[c][kk] = *(const bf16x8*)&Vl[cur][c * 16 + lr]
                                       [((kk * 4 + g) ^ (lr & 7)) * 8];
      }

#pragma unroll
    for (int qb = 0; qb < 4; ++qb) {
      // S^T = K·Q^T: lane holds s[c][r] = S[k=c*16+g*4+r][q=qb*16+lr]
      f32x4 s[4];
      __builtin_amdgcn_s_setprio(1);
#pragma unroll
      for (int c = 0; c < 4; ++c) {
        s[c] = __builtin_amdgcn_mfma_f32_16x16x32_bf16(kf[c][0], qf[qb][0], vzero, 0, 0, 0);
        s[c] = __builtin_amdgcn_mfma_f32_16x16x32_bf16(kf[c][1], qf[qb][1], s[c], 0, 0, 0);
      }
      __builtin_amdgcn_s_setprio(0);
      // exp (K pre-scaled) + pack to PV A-fragments.
      float p[4][4];
#pragma unroll
      for (int c = 0; c < 4; ++c)
#pragma unroll
        for (int r = 0; r < 4; ++r) p[c][r] = __builtin_amdgcn_exp2f(s[c][r]);
      // pf[kk] elem j: (c,r) = (kk*2+(j>>2), j&3)  [pi-permutation, V matches]
      bf16x8 pf[2];
#pragma unroll
      for (int kk = 0; kk < 2; ++kk) {
        uint4 w;
        w.x = cvtpk(p[kk * 2][0], p[kk * 2][1]);
        w.y = cvtpk(p[kk * 2][2], p[kk * 2][3]);
        w.z = cvtpk(p[kk * 2 + 1][0], p[kk * 2 + 1][1]);
        w.w = cvtpk(p[kk * 2 + 1][2], p[kk * 2 + 1][3]);
        pf[kk] = *(bf16x8*)&w;
      }
      // PV + l: o += P·V_perm ; ol += P·1  (same C-layout as o)
      __builtin_amdgcn_s_setprio(1);
      ol[qb] = __builtin_amdgcn_mfma_f32_16x16x32_bf16(pf[0], ones, ol[qb], 0, 0, 0);
      ol[qb] = __builtin_amdgcn_mfma_f32_16x16x32_bf16(pf[1], ones, ol[qb], 0, 0, 0);
#pragma unroll
      for (int d = 0; d < 4; ++d) {
        o[qb][d] = __builtin_amdgcn_mfma_f32_16x16x32_bf16(pf[0], vf[d][0], o[qb][d], 0, 0, 0);
        o[qb][d] = __builtin_amdgcn_mfma_f32_16x16x32_bf16(pf[1], vf[d][1], o[qb][d], 0, 0, 0);
      }
      __builtin_amdgcn_s_setprio(0);
    }
    // both halves: staged buf drained at the barrier (vmcnt 0 before s_barrier)
    __syncthreads();
  };

  __syncthreads();  // buf0 ready for both halves (drains stage(0) + Q loads)
#pragma unroll 1
  for (int tl = 0; tl < NTH; tl += 2) {
    tile(0, tl);      // literal buffer indices: ds addrs = base + imm offset
    tile(1, tl + 1);
  }

  // Combine halves (no-max softmax: partials add directly). Single barrier:
  // half-1 writes all 4 qb (20 f32/qb/lane, float4 stride 84), sync,
  // half-0 reads all. All o/ol indices compile-time (rule #20).
  if (half) {
#pragma unroll
    for (int qb = 0; qb < 4; ++qb) {
#pragma unroll
      for (int d = 0; d < 4; ++d)
        *(float4*)&cmb[wq][lane][qb * 20 + d * 4] = *(float4*)&o[qb][d];
      *(float4*)&cmb[wq][lane][qb * 20 + 16] = *(float4*)&ol[qb];
    }
  }
  __syncthreads();
  if (!half) {
#pragma unroll
    for (int qb = 0; qb < 4; ++qb) {
      float4 lo = *(float4*)&cmb[wq][lane][qb * 20 + 16];
      float linv[4];
      linv[0] = __builtin_amdgcn_rcpf(ol[qb][0] + lo.x);
      linv[1] = __builtin_amdgcn_rcpf(ol[qb][1] + lo.y);
      linv[2] = __builtin_amdgcn_rcpf(ol[qb][2] + lo.z);
      linv[3] = __builtin_amdgcn_rcpf(ol[qb][3] + lo.w);
#pragma unroll
      for (int d = 0; d < 4; ++d) {
        float4 oo = *(float4*)&cmb[wq][lane][qb * 20 + d * 4];
#pragma unroll
        for (int r = 0; r < 4; ++r) {
          float other = (r == 0) ? oo.x : (r == 1) ? oo.y : (r == 2) ? oo.z : oo.w;
          float val = (o[qb][d][r] + other) * linv[r];
          size_t row = (size_t)b * SS + q0 + wq * 64 + qb * 16 + g * 4 + r;
          ctx[row * DMODEL + h * 64 + d * 16 + lr] = f2bf(val);
        }
      }
    }
  }
}

// ---------------------------------------------------------------------------
// out[4096,1024] fp32 = ctx_bf16[4096,1024] @ Wb^T   (B^T-layout GEMM)
// 128x128 tile @ 512 threads (8 waves, 2x4 wave grid, acc[4][2]); LDS 64KB.
// R11: T1 XCD swizzle — 1D grid 256; m = (bid&7)*4 + ((bid>>3)&3),
// n = bid>>5: each XCD owns 4 complete A-panels (1MB) + shared W (2MB) in L2.
// ---------------------------------------------------------------------------
__global__ void __launch_bounds__(512, 1)
proj_gemm(const ushort_t* __restrict__ A, const ushort_t* __restrict__ Bw,
          float* __restrict__ out) {
  __shared__ ushort_t At[2][128][64];
  __shared__ ushort_t Bt[2][128][64];
  int bid = blockIdx.x;
  int m0 = ((bid & 7) * 4 + ((bid >> 3) & 3)) * 128;
  int n0 = (bid >> 5) * 128;
  int t = threadIdx.x;
  int wid = t >> 6, lane = t & 63;
  int wr = wid >> 2, wc = wid & 3;  // 2x4 wave grid: 64-row x 32-col tiles
  int g = lane >> 4, lr = lane & 15;
  int rsub = lane >> 3, ch = (lane & 7) ^ rsub;
  const f32x4 vzero = {0.f, 0.f, 0.f, 0.f};
  f32x4 acc[4][2];
#pragma unroll
  for (int m = 0; m < 4; ++m)
#pragma unroll
    for (int n = 0; n < 2; ++n) acc[m][n] = vzero;

  auto stage = [&](int buf, int k0) {
#pragma unroll
    for (int j = 0; j < 2; ++j) {
      int i = j * 8 + wid;  // 16 row-groups of 8 rows each for A and B
      gload16(A + (size_t)(m0 + i * 8 + rsub) * DMODEL + k0 + ch * 8, &At[buf][i * 8][0]);
      gload16(Bw + (size_t)(n0 + i * 8 + rsub) * DMODEL + k0 + ch * 8, &Bt[buf][i * 8][0]);
    }
  };

  const int NTK = DMODEL / 64;  // 16
  auto step = [&](int cur, int kt) {
    if (kt + 1 < NTK) stage(cur ^ 1, (kt + 1) * 64);
#pragma unroll
    for (int kk = 0; kk < 2; ++kk) {
      bf16x8 af[4], bf[2];
#pragma unroll
      for (int m = 0; m < 4; ++m)
        af[m] = *(const bf16x8*)&At[cur][wr * 64 + m * 16 + lr]
                                      [((kk * 4 + g) ^ (lr & 7)) * 8];
#pragma unroll
      for (int n = 0; n < 2; ++n)
        bf[n] = *(const bf16x8*)&Bt[cur][wc * 32 + n * 16 + lr]
                                      [((kk * 4 + g) ^ (lr & 7)) * 8];
#pragma unroll
      for (int m = 0; m < 4; ++m)
#pragma unroll
        for (int n = 0; n < 2; ++n)
          acc[m][n] = __builtin_amdgcn_mfma_f32_16x16x32_bf16(af[m], bf[n], acc[m][n], 0, 0, 0);
    }
    __syncthreads();
  };

  stage(0, 0);
  __syncthreads();
#pragma unroll 1
  for (int kt = 0; kt < NTK; kt += 2) {
    step(0, kt);
    step(1, kt + 1);
  }
#pragma unroll
  for (int m = 0; m < 4; ++m)
#pragma unroll
    for (int n = 0; n < 2; ++n)
#pragma unroll
      for (int r = 0; r < 4; ++r)
        out[(size_t)(m0 + wr * 64 + m * 16 + g * 4 + r) * DMODEL +
            n0 + wc * 32 + n * 16 + lr] = acc[m][n][r];
}

extern "C" void kernel_launch(void* const* d_in, const int* in_sizes, int n_in,
                              void* d_out, int out_size, void* d_ws, size_t ws_size,
                              hipStream_t stream) {
  const float* q = (const float*)d_in[0];
  const float* k = (const float*)d_in[1];
  const float* v = (const float*)d_in[2];
  const float* w = (const float*)d_in[3];
  float* out = (float*)d_out;

  size_t nqk = (size_t)BB * HH * SS * 64;  // 4,194,304 elems per tensor
  ushort_t* Kh = (ushort_t*)d_ws;
  ushort_t* Vt = Kh + nqk;
  ushort_t* ctx = Vt + nqk;
  ushort_t* Wb = ctx + (size_t)BB * SS * DMODEL;
  size_t need = (3 * nqk + (size_t)DMODEL * DMODEL) * sizeof(ushort_t);  // ~27 MB
  if (ws_size < need) return;

  conv_fused<<<1024 + 512, 256, 0, stream>>>(k, v, w, Kh, Vt, Wb);
  attn_fwd<<<256, 512, 0, stream>>>(q, Kh, Vt, ctx);
  proj_gemm<<<256, 512, 0, stream>>>(ctx, Wb, out);
}

// Round 13
// 68.469 us; speedup vs baseline: 2.1894x; 1.0023x over previous
//
#include <hip/hip_runtime.h>

#define BB 2
#define HH 16
#define SS 2048
#define DMODEL 1024

typedef unsigned short ushort_t;
typedef short bf16x8 __attribute__((ext_vector_type(8)));   // 8 bf16 = 4 VGPR
typedef float f32x4 __attribute__((ext_vector_type(4)));

__device__ __forceinline__ unsigned short f2bf(float f) {
  union { float f; unsigned int u; } x; x.f = f;
  unsigned int u = x.u;
  return (unsigned short)((u + 0x7fffu + ((u >> 16) & 1u)) >> 16);  // RNE
}
__device__ __forceinline__ unsigned int pack2(float a, float b) {
  return (unsigned int)f2bf(a) | ((unsigned int)f2bf(b) << 16);
}
// 2 f32 -> packed 2x bf16 in one instruction (gfx950; no builtin, T12 recipe)
__device__ __forceinline__ unsigned int cvtpk(float lo, float hi) {
  unsigned int r;
  asm("v_cvt_pk_bf16_f32 %0, %1, %2" : "=v"(r) : "v"(lo), "v"(hi));
  return r;
}
// async global->LDS, 16B per lane; LDS dest is wave-uniform base + lane*16
__device__ __forceinline__ void gload16(const ushort_t* g, ushort_t* l) {
  __builtin_amdgcn_global_load_lds(
      (const __attribute__((address_space(1))) void*)g,
      (__attribute__((address_space(3))) void*)l, 16, 0, 0);
}

// ---------------------------------------------------------------------------
// conv_kv + conv_w in one dispatch (1536 blocks: 1024 KV + 512 W).
// fp32 K,V [B,S,H*64] -> bf16 Kh (pre-scaled by log2(e)/8) [B,H,S,64];
// V -> Vt [B,H,64,S] with per-64-tile k-permutation matching attn's in-lane
// P layout (swapped-QK): Vt[d][64t + pi(m)] = V[64t + m][d],
// pi(c*16+g*4+r) = (c>>1)*32 + g*8 + (c&1)*4 + r.
// W fp32 [1024,1024] -> bf16 same layout. Streaming, no reuse: no swizzle.
// ---------------------------------------------------------------------------
__global__ void __launch_bounds__(256)
conv_fused(const float* __restrict__ k, const float* __restrict__ v,
           const float* __restrict__ w, ushort_t* __restrict__ Kh,
           ushort_t* __restrict__ Vt, ushort_t* __restrict__ wb) {
  int bid = blockIdx.x;
  int t = threadIdx.x;
  if (bid >= 1024) {  // ---- W part: 512 blocks, one thread per 8 elements
    int i = (bid - 1024) * 256 + t;
    float4 a = *(const float4*)(w + (size_t)i * 8);
    float4 bq = *(const float4*)(w + (size_t)i * 8 + 4);
    uint4 o;
    o.x = pack2(a.x, a.y);
    o.y = pack2(a.z, a.w);
    o.z = pack2(bq.x, bq.y);
    o.w = pack2(bq.z, bq.w);
    *(uint4*)(wb + (size_t)i * 8) = o;
    return;
  }
  // ---- KV part: 1024 blocks (32 s-blocks x 32 bh)
  const float c_sc = 0.18033688011112042f;  // log2(e)/sqrt(64): folded into K
  __shared__ float vlds[64][65];  // +1 pad: conflict-free column reads
  int bh = bid >> 5;
  int b = bh >> 4, h = bh & 15;
  int s0 = (bid & 31) * 64;
#pragma unroll
  for (int j = 0; j < 4; ++j) {
    int idx = t + j * 256;
    int r = idx >> 4, c4 = idx & 15;  // 64 s-rows x 16 float4 of the 64-wide head slice
    size_t in_off = ((size_t)(b * SS + s0 + r)) * DMODEL + h * 64 + c4 * 4;
    float4 ka = *(const float4*)(k + in_off);
    float4 va = *(const float4*)(v + in_off);
    size_t out_off = ((size_t)bh * SS + s0 + r) * 64 + c4 * 4;
    *(uint2*)(Kh + out_off) = make_uint2(pack2(ka.x * c_sc, ka.y * c_sc),
                                         pack2(ka.z * c_sc, ka.w * c_sc));
    vlds[r][c4 * 4 + 0] = va.x;
    vlds[r][c4 * 4 + 1] = va.y;
    vlds[r][c4 * 4 + 2] = va.z;
    vlds[r][c4 * 4 + 3] = va.w;
  }
  __syncthreads();
#pragma unroll
  for (int j = 0; j < 4; ++j) {
    int idx = t + j * 256;
    int d = idx >> 4, u = idx & 15;  // 64 d-rows x 16 chunks of 4 permuted-k
    int c = ((u >> 3) << 1) | (u & 1);
    int g = (u >> 1) & 3;
    int m0 = c * 16 + g * 4;
    size_t voff = ((size_t)bh * 64 + d) * SS + s0 + u * 4;
    *(uint2*)(Vt + voff) =
        make_uint2(pack2(vlds[m0 + 0][d], vlds[m0 + 1][d]),
                   pack2(vlds[m0 + 2][d], vlds[m0 + 3][d]));
  }
}

// ---------------------------------------------------------------------------
// Flash attention fwd, no-max online softmax. In-block KV-split (8 waves,
// q-tile 256, halves own kv tiles 0-15 / 16-31), XCD swizzle (R11: FETCH
// 73.8->16.5MB but dur flat => latency-structural, not BW).
// R12 (T4): counted-vmcnt pipeline, depth-2 prefetch, 4 LDS buffers/half.
// Per tile: s_waitcnt vmcnt(4) [tile-t loads landed, t+1 in flight] ->
// raw s_barrier -> stage(t+2) -> compute. Loads get ~2 compute phases of
// latency cover instead of <1 (the __syncthreads vmcnt(0)-drain stall).
// Q loaded FIRST (oldest vmcnt slots: its cvtpk waits don't drain stages).
// Combine buffer ALIASES staging LDS (dead after post-loop __syncthreads).
// ---------------------------------------------------------------------------
__global__ void __launch_bounds__(512, 1)
attn_fwd(const float* __restrict__ Qsrc, const ushort_t* __restrict__ Kh,
         const ushort_t* __restrict__ Vt, ushort_t* __restrict__ ctx) {
  // [half][buf][K=0/V=1][row][col] = 128 KB total
  __shared__ __align__(16) ushort_t KV[2][4][2][64][64];
  float (*cmb)[64][84] = (float(*)[64][84])&KV[0][0][0][0][0];  // alias, 86KB
  int bid = blockIdx.x;
  int bh = (bid & 7) * 4 + ((bid >> 3) & 3);  // XCD-resident bh group
  int q0 = (bid >> 5) * 256;
  int b = bh >> 4, h = bh & 15;
  int tid = threadIdx.x;
  int wid = tid >> 6;
  int half = wid >> 2;   // kv half: 0 -> tiles 0-15, 1 -> tiles 16-31
  int wq = wid & 3;      // q-row group within the half
  int lane = tid & 63;
  int g = lane >> 4, lr = lane & 15;
  int rsub = lane >> 3, ch = (lane & 7) ^ rsub;  // stage: row-in-8 / swizzled chunk

  const ushort_t* Kp = Kh + (size_t)bh * SS * 64;
  const ushort_t* Vp = Vt + (size_t)bh * 64 * SS;
  const int kvbase = half * (SS / 2);

  // Q fragments FIRST (oldest vmcnt slots). fp32 direct; scale is in Kh.
  bf16x8 qf[4][2];
#pragma unroll
  for (int qb = 0; qb < 4; ++qb) {
    int row = q0 + wq * 64 + qb * 16 + lr;
    const float* qr = Qsrc + ((size_t)(b * SS + row)) * DMODEL + h * 64;
#pragma unroll
    for (int kk = 0; kk < 2; ++kk) {
      float4 x = *(const float4*)(qr + kk * 32 + g * 8);
      float4 y = *(const float4*)(qr + kk * 32 + g * 8 + 4);
      uint4 wv;
      wv.x = cvtpk(x.x, x.y);
      wv.y = cvtpk(x.z, x.w);
      wv.z = cvtpk(y.x, y.y);
      wv.w = cvtpk(y.z, y.w);
      qf[qb][kk] = *(bf16x8*)&wv;
    }
  }

  const f32x4 vzero = {0.f, 0.f, 0.f, 0.f};
  const short ob = (short)0x3F80;  // bf16 1.0
  const bf16x8 ones = {ob, ob, ob, ob, ob, ob, ob, ob};
  f32x4 o[4][4];
  f32x4 ol[4];  // l via mfma(P, ones): row=g*4+r=q, all cols equal
#pragma unroll
  for (int qb = 0; qb < 4; ++qb) {
    ol[qb] = vzero;
#pragma unroll
    for (int d = 0; d < 4; ++d) o[qb][d] = vzero;
  }

  // Stage one 64-kv tile into buf (4 waves x 4 gload16/wave per half).
  // Pre-swizzled source: LDS[row][c] = G[row][c ^ (row&7)].
  auto stage = [&](int buf, int kv) {
#pragma unroll
    for (int j = 0; j < 2; ++j) {
      int i = j * 4 + wq;
      gload16(Kp + (size_t)(kv + i * 8 + rsub) * 64 + ch * 8, &KV[half][buf][0][i * 8][0]);
      gload16(Vp + (size_t)(i * 8 + rsub) * SS + kv + ch * 8, &KV[half][buf][1][i * 8][0]);
    }
  };

  auto computeTile = [&](int cur) {
    bf16x8 kf[4][2], vf[4][2];
#pragma unroll
    for (int c = 0; c < 4; ++c)
#pragma unroll
      for (int kk = 0; kk < 2; ++kk) {
        kf[c][kk] = *(const bf16x8*)&KV[half][cur][0][c * 16 + lr]
                                       [((kk * 4 + g) ^ (lr & 7)) * 8];
        vf[c][kk] = *(const bf16x8*)&KV[half][cur][1][c * 16 + lr]
                                       [((kk * 4 + g) ^ (lr & 7)) * 8];
      }
#pragma unroll
    for (int qb = 0; qb < 4; ++qb) {
      // S^T = K·Q^T: lane holds s[c][r] = S[k=c*16+g*4+r][q=qb*16+lr]
      f32x4 s[4];
      __builtin_amdgcn_s_setprio(1);
#pragma unroll
      for (int c = 0; c < 4; ++c) {
        s[c] = __builtin_amdgcn_mfma_f32_16x16x32_bf16(kf[c][0], qf[qb][0], vzero, 0, 0, 0);
        s[c] = __builtin_amdgcn_mfma_f32_16x16x32_bf16(kf[c][1], qf[qb][1], s[c], 0, 0, 0);
      }
      __builtin_amdgcn_s_setprio(0);
      float p[4][4];
#pragma unroll
      for (int c = 0; c < 4; ++c)
#pragma unroll
        for (int r = 0; r < 4; ++r) p[c][r] = __builtin_amdgcn_exp2f(s[c][r]);
      // pf[kk] elem j: (c,r) = (kk*2+(j>>2), j&3)  [pi-permutation, V matches]
      bf16x8 pf[2];
#pragma unroll
      for (int kk = 0; kk < 2; ++kk) {
        uint4 w;
        w.x = cvtpk(p[kk * 2][0], p[kk * 2][1]);
        w.y = cvtpk(p[kk * 2][2], p[kk * 2][3]);
        w.z = cvtpk(p[kk * 2 + 1][0], p[kk * 2 + 1][1]);
        w.w = cvtpk(p[kk * 2 + 1][2], p[kk * 2 + 1][3]);
        pf[kk] = *(bf16x8*)&w;
      }
      __builtin_amdgcn_s_setprio(1);
      ol[qb] = __builtin_amdgcn_mfma_f32_16x16x32_bf16(pf[0], ones, ol[qb], 0, 0, 0);
      ol[qb] = __builtin_amdgcn_mfma_f32_16x16x32_bf16(pf[1], ones, ol[qb], 0, 0, 0);
#pragma unroll
      for (int d = 0; d < 4; ++d) {
        o[qb][d] = __builtin_amdgcn_mfma_f32_16x16x32_bf16(pf[0], vf[d][0], o[qb][d], 0, 0, 0);
        o[qb][d] = __builtin_amdgcn_mfma_f32_16x16x32_bf16(pf[1], vf[d][1], o[qb][d], 0, 0, 0);
      }
      __builtin_amdgcn_s_setprio(0);
    }
  };

  // tile with counted wait: vmcnt(4) = tile-t's 4 loads landed, t+1's fly on.
  auto tileW4 = [&](int cur, int tl, int sbuf, bool dostage) {
    asm volatile("s_waitcnt vmcnt(4)" ::: "memory");
    __builtin_amdgcn_s_barrier();
    if (dostage) stage(sbuf, kvbase + (tl + 2) * 64);
    computeTile(cur);
  };

  stage(0, kvbase);            // depth-2 prologue (after Q: stages stay young)
  stage(1, kvbase + 64);

#pragma unroll 1
  for (int tb = 0; tb < 12; tb += 4) {
    tileW4(0, tb + 0, 2, true);
    tileW4(1, tb + 1, 3, true);
    tileW4(2, tb + 2, 0, true);
    tileW4(3, tb + 3, 1, true);
  }
  tileW4(0, 12, 2, true);      // stages tile 14
  tileW4(1, 13, 3, true);      // stages tile 15
  tileW4(2, 14, 0, false);
  asm volatile("s_waitcnt vmcnt(0)" ::: "memory");  // last tile: full drain
  __builtin_amdgcn_s_barrier();
  computeTile(3);

  __syncthreads();  // all waves done with staging LDS -> cmb alias safe

  // Combine halves (no-max softmax: partials add directly). Single barrier:
  // half-1 writes all 4 qb (20 f32/qb/lane, float4 stride 84), sync,
  // half-0 reads all. All o/ol indices compile-time (rule #20).
  if (half) {
#pragma unroll
    for (int qb = 0; qb < 4; ++qb) {
#pragma unroll
      for (int d = 0; d < 4; ++d)
        *(float4*)&cmb[wq][lane][qb * 20 + d * 4] = *(float4*)&o[qb][d];
      *(float4*)&cmb[wq][lane][qb * 20 + 16] = *(float4*)&ol[qb];
    }
  }
  __syncthreads();
  if (!half) {
#pragma unroll
    for (int qb = 0; qb < 4; ++qb) {
      float4 lo = *(float4*)&cmb[wq][lane][qb * 20 + 16];
      float linv[4];
      linv[0] = __builtin_amdgcn_rcpf(ol[qb][0] + lo.x);
      linv[1] = __builtin_amdgcn_rcpf(ol[qb][1] + lo.y);
      linv[2] = __builtin_amdgcn_rcpf(ol[qb][2] + lo.z);
      linv[3] = __builtin_amdgcn_rcpf(ol[qb][3] + lo.w);
#pragma unroll
      for (int d = 0; d < 4; ++d) {
        float4 oo = *(float4*)&cmb[wq][lane][qb * 20 + d * 4];
#pragma unroll
        for (int r = 0; r < 4; ++r) {
          float other = (r == 0) ? oo.x : (r == 1) ? oo.y : (r == 2) ? oo.z : oo.w;
          float val = (o[qb][d][r] + other) * linv[r];
          size_t row = (size_t)b * SS + q0 + wq * 64 + qb * 16 + g * 4 + r;
          ctx[row * DMODEL + h * 64 + d * 16 + lr] = f2bf(val);
        }
      }
    }
  }
}

// ---------------------------------------------------------------------------
// out[4096,1024] fp32 = ctx_bf16[4096,1024] @ Wb^T   (B^T-layout GEMM)
// 128x128 tile @ 512 threads (8 waves, 2x4 wave grid, acc[4][2]); LDS 64KB.
// T1 XCD swizzle — 1D grid 256; m = (bid&7)*4 + ((bid>>3)&3), n = bid>>5:
// each XCD owns 4 complete A-panels (1MB) + shared W (2MB) in its L2.
// ---------------------------------------------------------------------------
__global__ void __launch_bounds__(512, 1)
proj_gemm(const ushort_t* __restrict__ A, const ushort_t* __restrict__ Bw,
          float* __restrict__ out) {
  __shared__ ushort_t At[2][128][64];
  __shared__ ushort_t Bt[2][128][64];
  int bid = blockIdx.x;
  int m0 = ((bid & 7) * 4 + ((bid >> 3) & 3)) * 128;
  int n0 = (bid >> 5) * 128;
  int t = threadIdx.x;
  int wid = t >> 6, lane = t & 63;
  int wr = wid >> 2, wc = wid & 3;  // 2x4 wave grid: 64-row x 32-col tiles
  int g = lane >> 4, lr = lane & 15;
  int rsub = lane >> 3, ch = (lane & 7) ^ rsub;
  const f32x4 vzero = {0.f, 0.f, 0.f, 0.f};
  f32x4 acc[4][2];
#pragma unroll
  for (int m = 0; m < 4; ++m)
#pragma unroll
    for (int n = 0; n < 2; ++n) acc[m][n] = vzero;

  auto stage = [&](int buf, int k0) {
#pragma unroll
    for (int j = 0; j < 2; ++j) {
      int i = j * 8 + wid;  // 16 row-groups of 8 rows each for A and B
      gload16(A + (size_t)(m0 + i * 8 + rsub) * DMODEL + k0 + ch * 8, &At[buf][i * 8][0]);
      gload16(Bw + (size_t)(n0 + i * 8 + rsub) * DMODEL + k0 + ch * 8, &Bt[buf][i * 8][0]);
    }
  };

  const int NTK = DMODEL / 64;  // 16
  auto step = [&](int cur, int kt) {
    if (kt + 1 < NTK) stage(cur ^ 1, (kt + 1) * 64);
#pragma unroll
    for (int kk = 0; kk < 2; ++kk) {
      bf16x8 af[4], bf[2];
#pragma unroll
      for (int m = 0; m < 4; ++m)
        af[m] = *(const bf16x8*)&At[cur][wr * 64 + m * 16 + lr]
                                      [((kk * 4 + g) ^ (lr & 7)) * 8];
#pragma unroll
      for (int n = 0; n < 2; ++n)
        bf[n] = *(const bf16x8*)&Bt[cur][wc * 32 + n * 16 + lr]
                                      [((kk * 4 + g) ^ (lr & 7)) * 8];
#pragma unroll
      for (int m = 0; m < 4; ++m)
#pragma unroll
        for (int n = 0; n < 2; ++n)
          acc[m][n] = __builtin_amdgcn_mfma_f32_16x16x32_bf16(af[m], bf[n], acc[m][n], 0, 0, 0);
    }
    __syncthreads();
  };

  stage(0, 0);
  __syncthreads();
#pragma unroll 1
  for (int kt = 0; kt < NTK; kt += 2) {
    step(0, kt);
    step(1, kt + 1);
  }
#pragma unroll
  for (int m = 0; m < 4; ++m)
#pragma unroll
    for (int n = 0; n < 2; ++n)
#pragma unroll
      for (int r = 0; r < 4; ++r)
        out[(size_t)(m0 + wr * 64 + m * 16 + g * 4 + r) * DMODEL +
            n0 + wc * 32 + n * 16 + lr] = acc[m][n][r];
}

extern "C" void kernel_launch(void* const* d_in, const int* in_sizes, int n_in,
                              void* d_out, int out_size, void* d_ws, size_t ws_size,
                              hipStream_t stream) {
  const float* q = (const float*)d_in[0];
  const float* k = (const float*)d_in[1];
  const float* v = (const float*)d_in[2];
  const float* w = (const float*)d_in[3];
  float* out = (float*)d_out;

  size_t nqk = (size_t)BB * HH * SS * 64;  // 4,194,304 elems per tensor
  ushort_t* Kh = (ushort_t*)d_ws;
  ushort_t* Vt = Kh + nqk;
  ushort_t* ctx = Vt + nqk;
  ushort_t* Wb = ctx + (size_t)BB * SS * DMODEL;
  size_t need = (3 * nqk + (size_t)DMODEL * DMODEL) * sizeof(ushort_t);  // ~27 MB
  if (ws_size < need) return;

  conv_fused<<<1024 + 512, 256, 0, stream>>>(k, v, w, Kh, Vt, Wb);
  attn_fwd<<<256, 512, 0, stream>>>(q, Kh, Vt, ctx);
  proj_gemm<<<256, 512, 0, stream>>>(ctx, Wb, out);
}